// Round 1
// baseline (12409.589 us; speedup 1.0000x reference)
//
#include <hip/hip_runtime.h>
#include <hip/hip_bf16.h>

#define N_NODES 100000
#define N_EDGES 1600000
#define BATCH   256
#define HDIM    512

// ---------------- GEMM: C[M,N] = act(A[M,K] @ W[K,N] + bias) ----------------
// ACT: 0 = none, 1 = relu. 64x64 tile, BK=16, 256 threads, 4x4 per thread.
template<int ACT>
__global__ void gemm_kernel(const float* __restrict__ A, const float* __restrict__ W,
                            const float* __restrict__ bias, float* __restrict__ C,
                            int M, int K, int N) {
    __shared__ float As[64][17];
    __shared__ float Bs[16][65];
    const int tid = threadIdx.x;
    const int tx = tid & 15;
    const int ty = tid >> 4;
    const int row0 = blockIdx.y * 64;
    const int col0 = blockIdx.x * 64;
    float acc[4][4] = {};
    for (int k0 = 0; k0 < K; k0 += 16) {
        #pragma unroll
        for (int q = 0; q < 4; ++q) {
            int e = tid + q * 256;
            int r = e >> 4, kk = e & 15;
            int gr = row0 + r, gk = k0 + kk;
            As[r][kk] = (gr < M && gk < K) ? A[(size_t)gr * K + gk] : 0.f;
        }
        #pragma unroll
        for (int q = 0; q < 4; ++q) {
            int e = tid + q * 256;
            int kk = e >> 6, c = e & 63;
            int gk = k0 + kk, gc = col0 + c;
            Bs[kk][c] = (gk < K && gc < N) ? W[(size_t)gk * N + gc] : 0.f;
        }
        __syncthreads();
        #pragma unroll
        for (int kk = 0; kk < 16; ++kk) {
            float a[4], b[4];
            #pragma unroll
            for (int i = 0; i < 4; ++i) a[i] = As[ty * 4 + i][kk];
            #pragma unroll
            for (int j = 0; j < 4; ++j) b[j] = Bs[kk][tx * 4 + j];
            #pragma unroll
            for (int i = 0; i < 4; ++i)
                #pragma unroll
                for (int j = 0; j < 4; ++j)
                    acc[i][j] += a[i] * b[j];
        }
        __syncthreads();
    }
    #pragma unroll
    for (int i = 0; i < 4; ++i) {
        int gr = row0 + ty * 4 + i;
        if (gr >= M) continue;
        #pragma unroll
        for (int j = 0; j < 4; ++j) {
            int gc = col0 + tx * 4 + j;
            if (gc >= N) continue;
            float v = acc[i][j] + (bias ? bias[gc] : 0.f);
            if (ACT == 1) v = fmaxf(v, 0.f);
            C[(size_t)gr * N + gc] = v;
        }
    }
}

// ---------------- degree / normalization ----------------
__global__ void count_deg(const int* __restrict__ dst, float* __restrict__ deg, int E) {
    int i = blockIdx.x * blockDim.x + threadIdx.x;
    if (i < E) atomicAdd(&deg[dst[i]], 1.f);
}

__global__ void finalize_dis(float* __restrict__ d, int n) {
    int i = blockIdx.x * blockDim.x + threadIdx.x;
    if (i < n) d[i] = rsqrtf(d[i] + 1.f);
}

// ---------------- edge aggregation: agg[dst] += hw[src] * dis[src]*dis[dst] --
template<int C>
__global__ void edge_agg(const float* __restrict__ hw, const int* __restrict__ src,
                         const int* __restrict__ dst, const float* __restrict__ dis,
                         float* __restrict__ agg, int E) {
    constexpr int GPE = C / 4;           // float4 groups per edge
    int t = blockIdx.x * blockDim.x + threadIdx.x;
    int e = t / GPE;
    if (e >= E) return;
    int g = t - e * GPE;
    int s = src[e], d = dst[e];
    float norm = dis[s] * dis[d];
    const float4 v = *reinterpret_cast<const float4*>(hw + (size_t)s * C + g * 4);
    float* out = agg + (size_t)d * C + g * 4;
    atomicAdd(out + 0, v.x * norm);
    atomicAdd(out + 1, v.y * norm);
    atomicAdd(out + 2, v.z * norm);
    atomicAdd(out + 3, v.w * norm);
}

// ---------------- self-loop + bias + activation (in place on agg) -----------
// ACT: 0 = none, 2 = elu
template<int C, int ACT>
__global__ void selfloop_act(float* __restrict__ agg, const float* __restrict__ hw,
                             const float* __restrict__ dis, const float* __restrict__ bias) {
    int t = blockIdx.x * blockDim.x + threadIdx.x;
    if (t >= N_NODES * C) return;
    int i = t / C;
    int c = t - i * C;
    float di = dis[i];
    float v = agg[t] + hw[t] * di * di + bias[c];
    if (ACT == 2) v = v > 0.f ? v : expm1f(v);
    agg[t] = v;
}

// ---------------- per-graph mean pool --------------------------------------
__global__ void pool_accum(const float* __restrict__ h, const int* __restrict__ batch,
                           float* __restrict__ pooled, float* __restrict__ counts) {
    int t = blockIdx.x * blockDim.x + threadIdx.x;
    if (t >= N_NODES * 64) return;
    int i = t >> 6, g = t & 63;
    int b = batch[i];
    const float4 v = *reinterpret_cast<const float4*>(h + (size_t)i * 256 + g * 4);
    float* out = pooled + b * 256 + g * 4;
    atomicAdd(out + 0, v.x);
    atomicAdd(out + 1, v.y);
    atomicAdd(out + 2, v.z);
    atomicAdd(out + 3, v.w);
    if (g == 0) atomicAdd(&counts[b], 1.f);
}

__global__ void pool_div(float* __restrict__ pooled, const float* __restrict__ counts) {
    int t = blockIdx.x * blockDim.x + threadIdx.x;
    if (t < BATCH * 256) pooled[t] /= counts[t >> 8];
}

// ---------------- concat helper: copy src[M,CS] into out[M,CT] at colOff ----
__global__ void copy_block(const float* __restrict__ src, float* __restrict__ out,
                           int csLog, int CT, int colOff, int total) {
    int t = blockIdx.x * blockDim.x + threadIdx.x;
    if (t >= total) return;
    int r = t >> csLog;
    int c = t & ((1 << csLog) - 1);
    out[(size_t)r * CT + colOff + c] = src[t];
}

// ---------------- classifier heads + log_softmax ----------------------------
__global__ void heads_kernel(const float* __restrict__ fin, const float* __restrict__ Wb,
                             const float* __restrict__ bb, const float* __restrict__ Wa,
                             const float* __restrict__ ba, float* __restrict__ out) {
    int r = blockIdx.x * blockDim.x + threadIdx.x;
    if (r >= BATCH) return;
    float z0 = bb[0], z1 = bb[1], y0 = ba[0], y1 = ba[1];
    for (int k = 0; k < HDIM; ++k) {
        float f = fin[(size_t)r * HDIM + k];
        z0 += f * Wb[k * 2 + 0];
        z1 += f * Wb[k * 2 + 1];
        y0 += f * Wa[k * 2 + 0];
        y1 += f * Wa[k * 2 + 1];
    }
    float m = fmaxf(z0, z1);
    float l = m + logf(expf(z0 - m) + expf(z1 - m));
    out[r * 2 + 0] = z0 - l;
    out[r * 2 + 1] = z1 - l;
    float m2 = fmaxf(y0, y1);
    float l2 = m2 + logf(expf(y0 - m2) + expf(y1 - m2));
    out[512 + r * 2 + 0] = y0 - l2;
    out[512 + r * 2 + 1] = y1 - l2;
}

extern "C" void kernel_launch(void* const* d_in, const int* in_sizes, int n_in,
                              void* d_out, int out_size, void* d_ws, size_t ws_size,
                              hipStream_t stream) {
    // ---- inputs (setup_inputs order) ----
    const float* video = (const float*)d_in[1];
    const float* x     = (const float*)d_in[2];
    const int*   eidx  = (const int*)d_in[3];
    const int*   batch = (const int*)d_in[4];
    // d_in[0]=text, 5/6=Wt/bt, 9..12=Wq/bq/Wk/bk are dead (seq-len-1 softmax == 1,
    // text branch only feeds q).
    const float* Wv  = (const float*)d_in[7],  *bv  = (const float*)d_in[8];
    const float* Wva = (const float*)d_in[13], *bva = (const float*)d_in[14];
    const float* Wo  = (const float*)d_in[15], *bo  = (const float*)d_in[16];
    const float* Wf  = (const float*)d_in[17], *bf  = (const float*)d_in[18];
    const float* G1W = (const float*)d_in[19], *G1b = (const float*)d_in[20];
    const float* G2W = (const float*)d_in[21], *G2b = (const float*)d_in[22];
    const float* G3W = (const float*)d_in[23], *G3b = (const float*)d_in[24];
    const float* Wff = (const float*)d_in[25], *bff = (const float*)d_in[26];
    const float* Wb  = (const float*)d_in[27], *bb  = (const float*)d_in[28];
    const float* Wa  = (const float*)d_in[29], *ba  = (const float*)d_in[30];
    const int* srcE = eidx;
    const int* dstE = eidx + N_EDGES;

    // ---- workspace layout (floats) ----
    float* ws = (float*)d_ws;
    size_t off = 0;
    auto alloc = [&](size_t n) { float* p = ws + off; off += n; return p; };
    float* hwbuf  = alloc((size_t)N_NODES * 256);
    float* aggbuf = alloc((size_t)N_NODES * 256);
    float* dis    = alloc(N_NODES);
    float* venc   = alloc(BATCH * 512);
    float* vattn  = alloc(BATCH * 512);
    float* ta     = alloc(BATCH * 512);
    float* cat1   = alloc(BATCH * 1024);
    float* fusedb = alloc(BATCH * 512);
    float* pooled = alloc(BATCH * 256);
    float* counts = alloc(BATCH);
    float* cat2   = alloc(BATCH * 768);
    float* finalb = alloc(BATCH * 512);

    auto gemm = [&](const float* A, const float* W, const float* b, float* Cp,
                    int M, int K, int N, int act) {
        dim3 grid((N + 63) / 64, (M + 63) / 64);
        if (act == 1) gemm_kernel<1><<<grid, 256, 0, stream>>>(A, W, b, Cp, M, K, N);
        else          gemm_kernel<0><<<grid, 256, 0, stream>>>(A, W, b, Cp, M, K, N);
    };

    // ---- degree / dis ----
    hipMemsetAsync(dis, 0, N_NODES * sizeof(float), stream);
    count_deg<<<(N_EDGES + 255) / 256, 256, 0, stream>>>(dstE, dis, N_EDGES);
    finalize_dis<<<(N_NODES + 255) / 256, 256, 0, stream>>>(dis, N_NODES);

    // ---- front-end (video branch only; attention collapses to attn = v) ----
    gemm(video, Wv, bv, venc, BATCH, 512, 512, 1);
    gemm(venc, Wva, bva, vattn, BATCH, 512, 512, 0);
    gemm(vattn, Wo, bo, ta, BATCH, 512, 512, 0);
    copy_block<<<(BATCH * 512 + 255) / 256, 256, 0, stream>>>(ta, cat1, 9, 1024, 0, BATCH * 512);
    copy_block<<<(BATCH * 512 + 255) / 256, 256, 0, stream>>>(venc, cat1, 9, 1024, 512, BATCH * 512);
    gemm(cat1, Wf, bf, fusedb, BATCH, 1024, 512, 1);

    // ---- GCN layer 1: x[100k,64] -> h1[100k,128] ----
    gemm(x, G1W, nullptr, hwbuf, N_NODES, 64, 128, 0);
    hipMemsetAsync(aggbuf, 0, (size_t)N_NODES * 128 * sizeof(float), stream);
    edge_agg<128><<<((size_t)N_EDGES * 32 + 255) / 256, 256, 0, stream>>>(hwbuf, srcE, dstE, dis, aggbuf, N_EDGES);
    selfloop_act<128, 2><<<((size_t)N_NODES * 128 + 255) / 256, 256, 0, stream>>>(aggbuf, hwbuf, dis, G1b);

    // ---- GCN layer 2: h1 -> h2[100k,128] ----
    gemm(aggbuf, G2W, nullptr, hwbuf, N_NODES, 128, 128, 0);
    hipMemsetAsync(aggbuf, 0, (size_t)N_NODES * 128 * sizeof(float), stream);
    edge_agg<128><<<((size_t)N_EDGES * 32 + 255) / 256, 256, 0, stream>>>(hwbuf, srcE, dstE, dis, aggbuf, N_EDGES);
    selfloop_act<128, 2><<<((size_t)N_NODES * 128 + 255) / 256, 256, 0, stream>>>(aggbuf, hwbuf, dis, G2b);

    // ---- GCN layer 3: h2 -> h3[100k,256] (no elu) ----
    gemm(aggbuf, G3W, nullptr, hwbuf, N_NODES, 128, 256, 0);
    hipMemsetAsync(aggbuf, 0, (size_t)N_NODES * 256 * sizeof(float), stream);
    edge_agg<256><<<((size_t)N_EDGES * 64 + 255) / 256, 256, 0, stream>>>(hwbuf, srcE, dstE, dis, aggbuf, N_EDGES);
    selfloop_act<256, 0><<<((size_t)N_NODES * 256 + 255) / 256, 256, 0, stream>>>(aggbuf, hwbuf, dis, G3b);

    // ---- per-graph mean pool (pooled + counts are contiguous) ----
    hipMemsetAsync(pooled, 0, (BATCH * 256 + BATCH) * sizeof(float), stream);
    pool_accum<<<((size_t)N_NODES * 64 + 255) / 256, 256, 0, stream>>>(aggbuf, batch, pooled, counts);
    pool_div<<<(BATCH * 256 + 255) / 256, 256, 0, stream>>>(pooled, counts);

    // ---- final fusion + heads ----
    copy_block<<<(BATCH * 512 + 255) / 256, 256, 0, stream>>>(fusedb, cat2, 9, 768, 0, BATCH * 512);
    copy_block<<<(BATCH * 256 + 255) / 256, 256, 0, stream>>>(pooled, cat2, 8, 768, 512, BATCH * 256);
    gemm(cat2, Wff, bff, finalb, BATCH, 768, 512, 1);
    heads_kernel<<<1, 256, 0, stream>>>(finalb, Wb, bb, Wa, ba, (float*)d_out);
}

// Round 2
// 2701.714 us; speedup vs baseline: 4.5932x; 4.5932x over previous
//
#include <hip/hip_runtime.h>
#include <hip/hip_bf16.h>

#define N_NODES 100000
#define N_EDGES 1600000
#define BATCH   256
#define HDIM    512

// ================= GEMM: C[M,N] = act(A[M,K]@W[K,N] + bias) =================
// 128x128 tile, K-step 8, 256 threads, 8x8 per thread, k-major LDS.
// ACT: 0 none, 1 relu, 2 elu.  SCALE: multiply output row by dis[row].
template<int ACT, int SCALE>
__global__ void gemm128(const float* __restrict__ A, const float* __restrict__ W,
                        const float* __restrict__ bias, const float* __restrict__ dis,
                        float* __restrict__ C, int M, int K, int N) {
    __shared__ float As[8][132];
    __shared__ float Bs[8][132];
    const int tid = threadIdx.x;
    const int tx = tid & 15;          // output col group: col = tx*8
    const int ty = tid >> 4;          // output row group: row = ty*8
    const int row0 = blockIdx.y * 128;
    const int col0 = blockIdx.x * 128;
    float acc[8][8] = {};
    for (int k0 = 0; k0 < K; k0 += 8) {
        #pragma unroll
        for (int q = 0; q < 4; ++q) {          // A tile: 128 rows x 8 k
            int e = tid + q * 256;
            int r = e >> 3, kk = e & 7;
            int gr = row0 + r;
            As[kk][r] = (gr < M) ? A[(size_t)gr * K + k0 + kk] : 0.f;
        }
        #pragma unroll
        for (int q = 0; q < 4; ++q) {          // B tile: 8 k x 128 cols
            int e = tid + q * 256;
            int kk = e >> 7, c = e & 127;
            int gc = col0 + c;
            Bs[kk][c] = (gc < N) ? W[(size_t)(k0 + kk) * N + gc] : 0.f;
        }
        __syncthreads();
        #pragma unroll
        for (int kk = 0; kk < 8; ++kk) {
            float4 a0 = *(const float4*)&As[kk][ty * 8];
            float4 a1 = *(const float4*)&As[kk][ty * 8 + 4];
            float4 b0 = *(const float4*)&Bs[kk][tx * 8];
            float4 b1 = *(const float4*)&Bs[kk][tx * 8 + 4];
            float a[8] = {a0.x, a0.y, a0.z, a0.w, a1.x, a1.y, a1.z, a1.w};
            float b[8] = {b0.x, b0.y, b0.z, b0.w, b1.x, b1.y, b1.z, b1.w};
            #pragma unroll
            for (int i = 0; i < 8; ++i)
                #pragma unroll
                for (int j = 0; j < 8; ++j)
                    acc[i][j] += a[i] * b[j];
        }
        __syncthreads();
    }
    #pragma unroll
    for (int i = 0; i < 8; ++i) {
        int gr = row0 + ty * 8 + i;
        if (gr >= M) continue;
        float drow = SCALE ? dis[gr] : 1.f;
        #pragma unroll
        for (int j = 0; j < 8; ++j) {
            int gc = col0 + tx * 8 + j;
            if (gc >= N) continue;
            float v = acc[i][j] + bias[gc];
            if (ACT == 1) v = fmaxf(v, 0.f);
            if (ACT == 2) v = v > 0.f ? v : expm1f(v);
            C[(size_t)gr * N + gc] = v * drow;
        }
    }
}

// ================= degree / dis =================
__global__ void deg_count(const int* __restrict__ dst, int* __restrict__ deg, int E) {
    int i = blockIdx.x * blockDim.x + threadIdx.x;
    if (i < E) atomicAdd(&deg[dst[i]], 1);
}

__global__ void make_dis(const int* __restrict__ deg, float* __restrict__ dis, int n) {
    int i = blockIdx.x * blockDim.x + threadIdx.x;
    if (i < n) dis[i] = rsqrtf((float)deg[i] + 1.f);
}

// ================= exclusive scan (1024 elems/block) =================
__global__ void scan1(const int* __restrict__ in, int* __restrict__ out,
                      int* __restrict__ bsum, int n) {
    __shared__ int ts[256];
    const int tid = threadIdx.x;
    const int base = blockIdx.x * 1024;
    int v[4];
    #pragma unroll
    for (int i = 0; i < 4; ++i) {
        int idx = base + tid * 4 + i;
        v[i] = (idx < n) ? in[idx] : 0;
    }
    ts[tid] = v[0] + v[1] + v[2] + v[3];
    __syncthreads();
    for (int off = 1; off < 256; off <<= 1) {
        int val = (tid >= off) ? ts[tid - off] : 0;
        __syncthreads();
        ts[tid] += val;
        __syncthreads();
    }
    int run = (tid == 0) ? 0 : ts[tid - 1];
    if (tid == 255) bsum[blockIdx.x] = ts[255];
    #pragma unroll
    for (int i = 0; i < 4; ++i) {
        int idx = base + tid * 4 + i;
        if (idx < n) out[idx] = run;
        run += v[i];
    }
}

__global__ void scan2(int* __restrict__ bsum, int nb) {
    if (threadIdx.x == 0 && blockIdx.x == 0) {
        int run = 0;
        for (int i = 0; i < nb; ++i) { int t = bsum[i]; bsum[i] = run; run += t; }
    }
}

__global__ void scan3(int* __restrict__ out, const int* __restrict__ bsum, int n, int total) {
    int idx = blockIdx.x * 1024 + threadIdx.x * 4;
    int add = bsum[blockIdx.x];
    #pragma unroll
    for (int i = 0; i < 4; ++i)
        if (idx + i < n) out[idx + i] += add;
    if (blockIdx.x == 0 && threadIdx.x == 0) out[n] = total;
}

// ================= CSR scatter =================
__global__ void csr_scatter(const int* __restrict__ srcE, const int* __restrict__ dstE,
                            const int* __restrict__ rowptr, int* __restrict__ cursor,
                            int* __restrict__ csr_src, int E) {
    int e = blockIdx.x * blockDim.x + threadIdx.x;
    if (e >= E) return;
    int d = dstE[e];
    int pos = rowptr[d] + atomicAdd(&cursor[d], 1);
    csr_src[pos] = srcE[e];
}

// ================= Hs0 = dis * x  (64 cols) =================
__global__ void scale_rows64(const float* __restrict__ x, const float* __restrict__ dis,
                             float* __restrict__ out) {
    int t = blockIdx.x * blockDim.x + threadIdx.x;
    if (t >= N_NODES * 64) return;
    out[t] = x[t] * dis[t >> 6];
}

// ================= CSR aggregate: out[d] = dis[d]*(Hs[d] + sum Hs[src]) =====
// one wave per node, lane handles channels lane + 64k
template<int C>
__global__ void csr_agg(const float* __restrict__ Hs, const int* __restrict__ rowptr,
                        const int* __restrict__ csr_src, const float* __restrict__ dis,
                        float* __restrict__ out) {
    int node = blockIdx.x * 4 + (threadIdx.x >> 6);
    if (node >= N_NODES) return;
    int lane = threadIdx.x & 63;
    int s0 = rowptr[node], s1 = rowptr[node + 1];
    float acc[C / 64];
    #pragma unroll
    for (int k = 0; k < C / 64; ++k)
        acc[k] = Hs[(size_t)node * C + k * 64 + lane];    // self-loop term
    for (int e = s0; e < s1; ++e) {
        int s = csr_src[e];
        #pragma unroll
        for (int k = 0; k < C / 64; ++k)
            acc[k] += Hs[(size_t)s * C + k * 64 + lane];
    }
    float dd = dis[node];
    #pragma unroll
    for (int k = 0; k < C / 64; ++k)
        out[(size_t)node * C + k * 64 + lane] = acc[k] * dd;
}

// ================= chunked mean pool (batch_idx is sorted) =================
#define POOL_CHUNK 100
__global__ void pool_chunk(const float* __restrict__ h, const int* __restrict__ batch,
                           float* __restrict__ pooled, float* __restrict__ counts) {
    int c = threadIdx.x;                       // 256 channels
    int i0 = blockIdx.x * POOL_CHUNK;
    int i1 = min(i0 + POOL_CHUNK, N_NODES);
    float acc = 0.f;
    int cur = batch[i0], cnt = 0;
    for (int i = i0; i < i1; ++i) {
        int b = batch[i];
        if (b != cur) {
            atomicAdd(&pooled[cur * 256 + c], acc);
            if (c == 0) atomicAdd(&counts[cur], (float)cnt);
            acc = 0.f; cnt = 0; cur = b;
        }
        acc += h[(size_t)i * 256 + c];
        cnt++;
    }
    atomicAdd(&pooled[cur * 256 + c], acc);
    if (c == 0) atomicAdd(&counts[cur], (float)cnt);
}

__global__ void pool_div(float* __restrict__ pooled, const float* __restrict__ counts) {
    int t = blockIdx.x * blockDim.x + threadIdx.x;
    if (t < BATCH * 256) pooled[t] /= counts[t >> 8];
}

// ================= concat helper =================
__global__ void copy_block(const float* __restrict__ src, float* __restrict__ out,
                           int csLog, int CT, int colOff, int total) {
    int t = blockIdx.x * blockDim.x + threadIdx.x;
    if (t >= total) return;
    int r = t >> csLog;
    int c = t & ((1 << csLog) - 1);
    out[(size_t)r * CT + colOff + c] = src[t];
}

// ================= classifier heads + log_softmax =================
__global__ void heads_kernel(const float* __restrict__ fin, const float* __restrict__ Wb,
                             const float* __restrict__ bb, const float* __restrict__ Wa,
                             const float* __restrict__ ba, float* __restrict__ out) {
    int r = blockIdx.x * blockDim.x + threadIdx.x;
    if (r >= BATCH) return;
    float z0 = bb[0], z1 = bb[1], y0 = ba[0], y1 = ba[1];
    for (int k = 0; k < HDIM; ++k) {
        float f = fin[(size_t)r * HDIM + k];
        z0 += f * Wb[k * 2 + 0];
        z1 += f * Wb[k * 2 + 1];
        y0 += f * Wa[k * 2 + 0];
        y1 += f * Wa[k * 2 + 1];
    }
    float m = fmaxf(z0, z1);
    float l = m + logf(expf(z0 - m) + expf(z1 - m));
    out[r * 2 + 0] = z0 - l;
    out[r * 2 + 1] = z1 - l;
    float m2 = fmaxf(y0, y1);
    float l2 = m2 + logf(expf(y0 - m2) + expf(y1 - m2));
    out[512 + r * 2 + 0] = y0 - l2;
    out[512 + r * 2 + 1] = y1 - l2;
}

extern "C" void kernel_launch(void* const* d_in, const int* in_sizes, int n_in,
                              void* d_out, int out_size, void* d_ws, size_t ws_size,
                              hipStream_t stream) {
    // ---- inputs (setup_inputs order) ----
    const float* video = (const float*)d_in[1];
    const float* x     = (const float*)d_in[2];
    const int*   eidx  = (const int*)d_in[3];
    const int*   batch = (const int*)d_in[4];
    // text branch + Wq/Wk are dead: seq-len-1 softmax == 1 -> attn = v.
    const float* Wv  = (const float*)d_in[7],  *bv  = (const float*)d_in[8];
    const float* Wva = (const float*)d_in[13], *bva = (const float*)d_in[14];
    const float* Wo  = (const float*)d_in[15], *bo  = (const float*)d_in[16];
    const float* Wf  = (const float*)d_in[17], *bf  = (const float*)d_in[18];
    const float* G1W = (const float*)d_in[19], *G1b = (const float*)d_in[20];
    const float* G2W = (const float*)d_in[21], *G2b = (const float*)d_in[22];
    const float* G3W = (const float*)d_in[23], *G3b = (const float*)d_in[24];
    const float* Wff = (const float*)d_in[25], *bff = (const float*)d_in[26];
    const float* Wb  = (const float*)d_in[27], *bb  = (const float*)d_in[28];
    const float* Wa  = (const float*)d_in[29], *ba  = (const float*)d_in[30];
    const int* srcE = eidx;
    const int* dstE = eidx + N_EDGES;

    // ---- workspace layout ----
    char* wsc = (char*)d_ws;
    size_t off = 0;
    auto alloc = [&](size_t bytes) { char* p = wsc + off; off += (bytes + 255) & ~(size_t)255; return p; };
    float* bufA   = (float*)alloc((size_t)N_NODES * 256 * 4);  // Hs / h3
    float* bufB   = (float*)alloc((size_t)N_NODES * 128 * 4);  // agg outputs
    float* dis    = (float*)alloc(N_NODES * 4);
    int*   deg    = (int*)  alloc(N_NODES * 4);
    int*   rowptr = (int*)  alloc((N_NODES + 1) * 4);
    int*   cursor = (int*)  alloc(N_NODES * 4);
    int*   csrsrc = (int*)  alloc((size_t)N_EDGES * 4);
    int*   bsum   = (int*)  alloc(128 * 4);
    float* venc   = (float*)alloc(BATCH * 512 * 4);
    float* vattn  = (float*)alloc(BATCH * 512 * 4);
    float* ta     = (float*)alloc(BATCH * 512 * 4);
    float* cat1   = (float*)alloc(BATCH * 1024 * 4);
    float* fusedb = (float*)alloc(BATCH * 512 * 4);
    float* pooled = (float*)alloc(BATCH * 256 * 4);
    float* counts = (float*)alloc(BATCH * 4);
    float* cat2   = (float*)alloc(BATCH * 768 * 4);
    float* finalb = (float*)alloc(BATCH * 512 * 4);

    auto gemm = [&](const float* A, const float* W, const float* b, const float* sc,
                    float* Cp, int M, int K, int N, int act, int scale) {
        dim3 grid((N + 127) / 128, (M + 127) / 128);
        if (act == 0 && scale == 0) gemm128<0,0><<<grid, 256, 0, stream>>>(A, W, b, sc, Cp, M, K, N);
        if (act == 1 && scale == 0) gemm128<1,0><<<grid, 256, 0, stream>>>(A, W, b, sc, Cp, M, K, N);
        if (act == 2 && scale == 1) gemm128<2,1><<<grid, 256, 0, stream>>>(A, W, b, sc, Cp, M, K, N);
    };

    const int NB = (N_NODES + 1023) / 1024;   // 98

    // ---- degree, dis, CSR ----
    hipMemsetAsync(deg, 0, N_NODES * 4, stream);
    hipMemsetAsync(cursor, 0, N_NODES * 4, stream);
    deg_count<<<(N_EDGES + 255) / 256, 256, 0, stream>>>(dstE, deg, N_EDGES);
    make_dis<<<(N_NODES + 255) / 256, 256, 0, stream>>>(deg, dis, N_NODES);
    scan1<<<NB, 256, 0, stream>>>(deg, rowptr, bsum, N_NODES);
    scan2<<<1, 64, 0, stream>>>(bsum, NB);
    scan3<<<NB, 256, 0, stream>>>(rowptr, bsum, N_NODES, N_EDGES);
    csr_scatter<<<(N_EDGES + 255) / 256, 256, 0, stream>>>(srcE, dstE, rowptr, cursor, csrsrc, N_EDGES);

    // ---- front-end (video branch only) ----
    gemm(video, Wv, bv, nullptr, venc, BATCH, 512, 512, 1, 0);
    gemm(venc, Wva, bva, nullptr, vattn, BATCH, 512, 512, 0, 0);
    gemm(vattn, Wo, bo, nullptr, ta, BATCH, 512, 512, 0, 0);
    copy_block<<<(BATCH * 512 + 255) / 256, 256, 0, stream>>>(ta, cat1, 9, 1024, 0, BATCH * 512);
    copy_block<<<(BATCH * 512 + 255) / 256, 256, 0, stream>>>(venc, cat1, 9, 1024, 512, BATCH * 512);
    gemm(cat1, Wf, bf, nullptr, fusedb, BATCH, 1024, 512, 1, 0);

    // ---- GCN stack: aggregate-first ( Â(HW) == (ÂH)W ), Hs = dis .* H -----
    const int aggGrid = (N_NODES + 3) / 4;
    scale_rows64<<<(N_NODES * 64 + 255) / 256, 256, 0, stream>>>(x, dis, bufA);
    csr_agg<64><<<aggGrid, 256, 0, stream>>>(bufA, rowptr, csrsrc, dis, bufB);
    gemm(bufB, G1W, G1b, dis, bufA, N_NODES, 64, 128, 2, 1);     // Hs1 = dis*elu(.)
    csr_agg<128><<<aggGrid, 256, 0, stream>>>(bufA, rowptr, csrsrc, dis, bufB);
    gemm(bufB, G2W, G2b, dis, bufA, N_NODES, 128, 128, 2, 1);    // Hs2
    csr_agg<128><<<aggGrid, 256, 0, stream>>>(bufA, rowptr, csrsrc, dis, bufB);
    gemm(bufB, G3W, G3b, nullptr, bufA, N_NODES, 128, 256, 0, 0); // h3 [100k,256]

    // ---- per-graph mean pool ----
    hipMemsetAsync(pooled, 0, (BATCH * 256 + BATCH) * 4, stream);
    pool_chunk<<<(N_NODES + POOL_CHUNK - 1) / POOL_CHUNK, 256, 0, stream>>>(bufA, batch, pooled, counts);
    pool_div<<<(BATCH * 256 + 255) / 256, 256, 0, stream>>>(pooled, counts);

    // ---- final fusion + heads ----
    copy_block<<<(BATCH * 512 + 255) / 256, 256, 0, stream>>>(fusedb, cat2, 9, 768, 0, BATCH * 512);
    copy_block<<<(BATCH * 256 + 255) / 256, 256, 0, stream>>>(pooled, cat2, 8, 768, 512, BATCH * 256);
    gemm(cat2, Wff, bff, nullptr, finalb, BATCH, 768, 512, 1, 0);
    heads_kernel<<<1, 256, 0, stream>>>(finalb, Wb, bb, Wa, ba, (float*)d_out);
}

// Round 3
// 1457.764 us; speedup vs baseline: 8.5128x; 1.8533x over previous
//
#include <hip/hip_runtime.h>
#include <hip/hip_bf16.h>

#define N_NODES 100000
#define N_EDGES 1600000
#define BATCH   256
#define HDIM    512

// ================= GEMM: C[M,N] = act(A[M,K]@W[K,N] + bias) =================
// 128x128 tile, K-step 8, 256 threads, 8x8 per thread, k-major LDS.
// ACT: 0 none, 1 relu, 2 elu.  SCALE: multiply output row by dis[row].
// Used only for the node-feature GEMMs (M = 100000).
template<int ACT, int SCALE>
__global__ void gemm128(const float* __restrict__ A, const float* __restrict__ W,
                        const float* __restrict__ bias, const float* __restrict__ dis,
                        float* __restrict__ C, int M, int K, int N) {
    __shared__ float As[8][132];
    __shared__ float Bs[8][132];
    const int tid = threadIdx.x;
    const int tx = tid & 15;
    const int ty = tid >> 4;
    const int row0 = blockIdx.y * 128;
    const int col0 = blockIdx.x * 128;
    float acc[8][8] = {};
    for (int k0 = 0; k0 < K; k0 += 8) {
        #pragma unroll
        for (int q = 0; q < 4; ++q) {
            int e = tid + q * 256;
            int r = e >> 3, kk = e & 7;
            int gr = row0 + r;
            As[kk][r] = (gr < M) ? A[(size_t)gr * K + k0 + kk] : 0.f;
        }
        #pragma unroll
        for (int q = 0; q < 4; ++q) {
            int e = tid + q * 256;
            int kk = e >> 7, c = e & 127;
            int gc = col0 + c;
            Bs[kk][c] = (gc < N) ? W[(size_t)(k0 + kk) * N + gc] : 0.f;
        }
        __syncthreads();
        #pragma unroll
        for (int kk = 0; kk < 8; ++kk) {
            float4 a0 = *(const float4*)&As[kk][ty * 8];
            float4 a1 = *(const float4*)&As[kk][ty * 8 + 4];
            float4 b0 = *(const float4*)&Bs[kk][tx * 8];
            float4 b1 = *(const float4*)&Bs[kk][tx * 8 + 4];
            float a[8] = {a0.x, a0.y, a0.z, a0.w, a1.x, a1.y, a1.z, a1.w};
            float b[8] = {b0.x, b0.y, b0.z, b0.w, b1.x, b1.y, b1.z, b1.w};
            #pragma unroll
            for (int i = 0; i < 8; ++i)
                #pragma unroll
                for (int j = 0; j < 8; ++j)
                    acc[i][j] += a[i] * b[j];
        }
        __syncthreads();
    }
    #pragma unroll
    for (int i = 0; i < 8; ++i) {
        int gr = row0 + ty * 8 + i;
        if (gr >= M) continue;
        float drow = SCALE ? dis[gr] : 1.f;
        #pragma unroll
        for (int j = 0; j < 8; ++j) {
            int gc = col0 + tx * 8 + j;
            if (gc >= N) continue;
            float v = acc[i][j] + bias[gc];
            if (ACT == 1) v = fmaxf(v, 0.f);
            if (ACT == 2) v = v > 0.f ? v : expm1f(v);
            C[(size_t)gr * N + gc] = v * drow;
        }
    }
}

// ================= fused front-end: one block per batch row ==================
// venc = relu(video@Wv+bv); vattn = venc@Wva+bva; ta = vattn@Wo+bo;
// fused = relu([ta|venc]@Wf+bf)      (attention collapses: seq len 1 => attn=v)
__global__ void frontend_fused(const float* __restrict__ video,
                               const float* __restrict__ Wv,  const float* __restrict__ bv,
                               const float* __restrict__ Wva, const float* __restrict__ bva,
                               const float* __restrict__ Wo,  const float* __restrict__ bo,
                               const float* __restrict__ Wf,  const float* __restrict__ bf,
                               float* __restrict__ fusedb) {
    __shared__ float vin[512], venc[512], vattn[512], ta[512];
    const int b = blockIdx.x, tid = threadIdx.x;
    vin[tid] = video[b * 512 + tid];
    vin[tid + 256] = video[b * 512 + 256 + tid];
    __syncthreads();
    // venc
    {
        float a0 = bv[tid], a1 = bv[tid + 256];
        #pragma unroll 8
        for (int k = 0; k < 512; ++k) {
            float xv = vin[k];
            a0 += xv * Wv[k * 512 + tid];
            a1 += xv * Wv[k * 512 + tid + 256];
        }
        venc[tid] = fmaxf(a0, 0.f);
        venc[tid + 256] = fmaxf(a1, 0.f);
    }
    __syncthreads();
    // vattn ( = v of the attention )
    {
        float a0 = bva[tid], a1 = bva[tid + 256];
        #pragma unroll 8
        for (int k = 0; k < 512; ++k) {
            float xv = venc[k];
            a0 += xv * Wva[k * 512 + tid];
            a1 += xv * Wva[k * 512 + tid + 256];
        }
        vattn[tid] = a0;
        vattn[tid + 256] = a1;
    }
    __syncthreads();
    // ta = vattn @ Wo + bo
    {
        float a0 = bo[tid], a1 = bo[tid + 256];
        #pragma unroll 8
        for (int k = 0; k < 512; ++k) {
            float xv = vattn[k];
            a0 += xv * Wo[k * 512 + tid];
            a1 += xv * Wo[k * 512 + tid + 256];
        }
        ta[tid] = a0;
        ta[tid + 256] = a1;
    }
    __syncthreads();
    // fused = relu([ta | venc] @ Wf + bf)
    {
        float a0 = bf[tid], a1 = bf[tid + 256];
        #pragma unroll 8
        for (int k = 0; k < 512; ++k) {
            float xv = ta[k];
            a0 += xv * Wf[k * 512 + tid];
            a1 += xv * Wf[k * 512 + tid + 256];
        }
        #pragma unroll 8
        for (int k = 0; k < 512; ++k) {
            float xv = venc[k];
            a0 += xv * Wf[(512 + k) * 512 + tid];
            a1 += xv * Wf[(512 + k) * 512 + tid + 256];
        }
        fusedb[b * 512 + tid] = fmaxf(a0, 0.f);
        fusedb[b * 512 + tid + 256] = fmaxf(a1, 0.f);
    }
}

// ====== fused tail: final = relu([fused|pooled/cnt]@Wff+bff); 2 heads ========
__global__ void final_fused(const float* __restrict__ fusedb,
                            const float* __restrict__ pooled, const float* __restrict__ counts,
                            const float* __restrict__ Wff, const float* __restrict__ bff,
                            const float* __restrict__ Wb,  const float* __restrict__ bb,
                            const float* __restrict__ Wa,  const float* __restrict__ ba,
                            float* __restrict__ out) {
    __shared__ float cat[768], fin[512];
    __shared__ float rd[4][4];
    const int b = blockIdx.x, tid = threadIdx.x;
    cat[tid] = fusedb[b * 512 + tid];
    cat[tid + 256] = fusedb[b * 512 + 256 + tid];
    float inv = 1.f / counts[b];
    cat[512 + tid] = pooled[b * 256 + tid] * inv;
    __syncthreads();
    {
        float a0 = bff[tid], a1 = bff[tid + 256];
        #pragma unroll 8
        for (int k = 0; k < 768; ++k) {
            float xv = cat[k];
            a0 += xv * Wff[k * 512 + tid];
            a1 += xv * Wff[k * 512 + tid + 256];
        }
        fin[tid] = fmaxf(a0, 0.f);
        fin[tid + 256] = fmaxf(a1, 0.f);
    }
    __syncthreads();
    // heads
    float z0 = 0.f, z1 = 0.f, y0 = 0.f, y1 = 0.f;
    for (int k = tid; k < 512; k += 256) {
        float f = fin[k];
        z0 += f * Wb[2 * k];
        z1 += f * Wb[2 * k + 1];
        y0 += f * Wa[2 * k];
        y1 += f * Wa[2 * k + 1];
    }
    #pragma unroll
    for (int off = 32; off > 0; off >>= 1) {
        z0 += __shfl_down(z0, off);
        z1 += __shfl_down(z1, off);
        y0 += __shfl_down(y0, off);
        y1 += __shfl_down(y1, off);
    }
    int w = tid >> 6;
    if ((tid & 63) == 0) { rd[w][0] = z0; rd[w][1] = z1; rd[w][2] = y0; rd[w][3] = y1; }
    __syncthreads();
    if (tid == 0) {
        float Z0 = rd[0][0] + rd[1][0] + rd[2][0] + rd[3][0] + bb[0];
        float Z1 = rd[0][1] + rd[1][1] + rd[2][1] + rd[3][1] + bb[1];
        float Y0 = rd[0][2] + rd[1][2] + rd[2][2] + rd[3][2] + ba[0];
        float Y1 = rd[0][3] + rd[1][3] + rd[2][3] + rd[3][3] + ba[1];
        float m = fmaxf(Z0, Z1);
        float l = m + logf(expf(Z0 - m) + expf(Z1 - m));
        out[b * 2 + 0] = Z0 - l;
        out[b * 2 + 1] = Z1 - l;
        float m2 = fmaxf(Y0, Y1);
        float l2 = m2 + logf(expf(Y0 - m2) + expf(Y1 - m2));
        out[512 + b * 2 + 0] = Y0 - l2;
        out[512 + b * 2 + 1] = Y1 - l2;
    }
}

// ================= degree / dis =================
__global__ void deg_count(const int* __restrict__ dst, int* __restrict__ deg, int E) {
    int i = blockIdx.x * blockDim.x + threadIdx.x;
    if (i < E) atomicAdd(&deg[dst[i]], 1);
}

__global__ void make_dis(const int* __restrict__ deg, float* __restrict__ dis, int n) {
    int i = blockIdx.x * blockDim.x + threadIdx.x;
    if (i < n) dis[i] = rsqrtf((float)deg[i] + 1.f);
}

// ================= exclusive scan (1024 elems/block) =================
__global__ void scan1(const int* __restrict__ in, int* __restrict__ out,
                      int* __restrict__ bsum, int n) {
    __shared__ int ts[256];
    const int tid = threadIdx.x;
    const int base = blockIdx.x * 1024;
    int v[4];
    #pragma unroll
    for (int i = 0; i < 4; ++i) {
        int idx = base + tid * 4 + i;
        v[i] = (idx < n) ? in[idx] : 0;
    }
    ts[tid] = v[0] + v[1] + v[2] + v[3];
    __syncthreads();
    for (int off = 1; off < 256; off <<= 1) {
        int val = (tid >= off) ? ts[tid - off] : 0;
        __syncthreads();
        ts[tid] += val;
        __syncthreads();
    }
    int run = (tid == 0) ? 0 : ts[tid - 1];
    if (tid == 255) bsum[blockIdx.x] = ts[255];
    #pragma unroll
    for (int i = 0; i < 4; ++i) {
        int idx = base + tid * 4 + i;
        if (idx < n) out[idx] = run;
        run += v[i];
    }
}

__global__ void scan2(int* __restrict__ bsum, int nb) {
    if (threadIdx.x == 0 && blockIdx.x == 0) {
        int run = 0;
        for (int i = 0; i < nb; ++i) { int t = bsum[i]; bsum[i] = run; run += t; }
    }
}

__global__ void scan3(int* __restrict__ out, const int* __restrict__ bsum, int n, int total) {
    int idx = blockIdx.x * 1024 + threadIdx.x * 4;
    int add = bsum[blockIdx.x];
    #pragma unroll
    for (int i = 0; i < 4; ++i)
        if (idx + i < n) out[idx + i] += add;
    if (blockIdx.x == 0 && threadIdx.x == 0) out[n] = total;
}

// ================= CSR scatter =================
__global__ void csr_scatter(const int* __restrict__ srcE, const int* __restrict__ dstE,
                            const int* __restrict__ rowptr, int* __restrict__ cursor,
                            int* __restrict__ csr_src, int E) {
    int e = blockIdx.x * blockDim.x + threadIdx.x;
    if (e >= E) return;
    int d = dstE[e];
    int pos = rowptr[d] + atomicAdd(&cursor[d], 1);
    csr_src[pos] = srcE[e];
}

// ================= Hs0 = dis * x  (64 cols) =================
__global__ void scale_rows64(const float* __restrict__ x, const float* __restrict__ dis,
                             float* __restrict__ out) {
    int t = blockIdx.x * blockDim.x + threadIdx.x;
    if (t >= N_NODES * 64) return;
    out[t] = x[t] * dis[t >> 6];
}

// ========== CSR aggregate: out[d] = dis[d]*(Hs[d] + sum_{s->d} Hs[s]) ========
template<int C>
__global__ void csr_agg(const float* __restrict__ Hs, const int* __restrict__ rowptr,
                        const int* __restrict__ csr_src, const float* __restrict__ dis,
                        float* __restrict__ out) {
    int node = blockIdx.x * 4 + (threadIdx.x >> 6);
    if (node >= N_NODES) return;
    int lane = threadIdx.x & 63;
    int s0 = rowptr[node], s1 = rowptr[node + 1];
    float acc[C / 64];
    #pragma unroll
    for (int k = 0; k < C / 64; ++k)
        acc[k] = Hs[(size_t)node * C + k * 64 + lane];
    for (int e = s0; e < s1; ++e) {
        int s = csr_src[e];
        #pragma unroll
        for (int k = 0; k < C / 64; ++k)
            acc[k] += Hs[(size_t)s * C + k * 64 + lane];
    }
    float dd = dis[node];
    #pragma unroll
    for (int k = 0; k < C / 64; ++k)
        out[(size_t)node * C + k * 64 + lane] = acc[k] * dd;
}

// ================= chunked mean pool (batch_idx is sorted) =================
#define POOL_CHUNK 100
__global__ void pool_chunk(const float* __restrict__ h, const int* __restrict__ batch,
                           float* __restrict__ pooled, float* __restrict__ counts) {
    int c = threadIdx.x;
    int i0 = blockIdx.x * POOL_CHUNK;
    int i1 = min(i0 + POOL_CHUNK, N_NODES);
    float acc = 0.f;
    int cur = batch[i0], cnt = 0;
    for (int i = i0; i < i1; ++i) {
        int b = batch[i];
        if (b != cur) {
            atomicAdd(&pooled[cur * 256 + c], acc);
            if (c == 0) atomicAdd(&counts[cur], (float)cnt);
            acc = 0.f; cnt = 0; cur = b;
        }
        acc += h[(size_t)i * 256 + c];
        cnt++;
    }
    atomicAdd(&pooled[cur * 256 + c], acc);
    if (c == 0) atomicAdd(&counts[cur], (float)cnt);
}

extern "C" void kernel_launch(void* const* d_in, const int* in_sizes, int n_in,
                              void* d_out, int out_size, void* d_ws, size_t ws_size,
                              hipStream_t stream) {
    // ---- inputs (setup_inputs order) ----
    const float* video = (const float*)d_in[1];
    const float* x     = (const float*)d_in[2];
    const int*   eidx  = (const int*)d_in[3];
    const int*   batch = (const int*)d_in[4];
    // text branch + Wq/Wk are dead: seq-len-1 softmax == 1 -> attn = v.
    const float* Wv  = (const float*)d_in[7],  *bv  = (const float*)d_in[8];
    const float* Wva = (const float*)d_in[13], *bva = (const float*)d_in[14];
    const float* Wo  = (const float*)d_in[15], *bo  = (const float*)d_in[16];
    const float* Wf  = (const float*)d_in[17], *bf  = (const float*)d_in[18];
    const float* G1W = (const float*)d_in[19], *G1b = (const float*)d_in[20];
    const float* G2W = (const float*)d_in[21], *G2b = (const float*)d_in[22];
    const float* G3W = (const float*)d_in[23], *G3b = (const float*)d_in[24];
    const float* Wff = (const float*)d_in[25], *bff = (const float*)d_in[26];
    const float* Wb  = (const float*)d_in[27], *bb  = (const float*)d_in[28];
    const float* Wa  = (const float*)d_in[29], *ba  = (const float*)d_in[30];
    const int* srcE = eidx;
    const int* dstE = eidx + N_EDGES;

    // ---- workspace layout ----
    char* wsc = (char*)d_ws;
    size_t off = 0;
    auto alloc = [&](size_t bytes) { char* p = wsc + off; off += (bytes + 255) & ~(size_t)255; return p; };
    float* bufA   = (float*)alloc((size_t)N_NODES * 256 * 4);
    float* bufB   = (float*)alloc((size_t)N_NODES * 128 * 4);
    float* dis    = (float*)alloc(N_NODES * 4);
    int*   deg    = (int*)  alloc(N_NODES * 4);
    int*   rowptr = (int*)  alloc((N_NODES + 1) * 4);
    int*   cursor = (int*)  alloc(N_NODES * 4);
    int*   csrsrc = (int*)  alloc((size_t)N_EDGES * 4);
    int*   bsum   = (int*)  alloc(128 * 4);
    float* fusedb = (float*)alloc(BATCH * 512 * 4);
    float* pooled = (float*)alloc(BATCH * 256 * 4);
    float* counts = (float*)alloc(BATCH * 4);

    auto gemm = [&](const float* A, const float* W, const float* b, const float* sc,
                    float* Cp, int M, int K, int N, int act, int scale) {
        dim3 grid((N + 127) / 128, (M + 127) / 128);
        if (act == 0 && scale == 0) gemm128<0,0><<<grid, 256, 0, stream>>>(A, W, b, sc, Cp, M, K, N);
        if (act == 2 && scale == 1) gemm128<2,1><<<grid, 256, 0, stream>>>(A, W, b, sc, Cp, M, K, N);
    };

    const int NB = (N_NODES + 1023) / 1024;   // 98

    // ---- degree, dis, CSR ----
    hipMemsetAsync(deg, 0, N_NODES * 4, stream);
    hipMemsetAsync(cursor, 0, N_NODES * 4, stream);
    deg_count<<<(N_EDGES + 255) / 256, 256, 0, stream>>>(dstE, deg, N_EDGES);
    make_dis<<<(N_NODES + 255) / 256, 256, 0, stream>>>(deg, dis, N_NODES);
    scan1<<<NB, 256, 0, stream>>>(deg, rowptr, bsum, N_NODES);
    scan2<<<1, 64, 0, stream>>>(bsum, NB);
    scan3<<<NB, 256, 0, stream>>>(rowptr, bsum, N_NODES, N_EDGES);
    csr_scatter<<<(N_EDGES + 255) / 256, 256, 0, stream>>>(srcE, dstE, rowptr, cursor, csrsrc, N_EDGES);

    // ---- fused front-end (one block per batch row) ----
    frontend_fused<<<BATCH, 256, 0, stream>>>(video, Wv, bv, Wva, bva, Wo, bo, Wf, bf, fusedb);

    // ---- GCN stack: aggregate-first ( Â(HW) == (ÂH)W ), Hs = dis .* H -----
    const int aggGrid = (N_NODES + 3) / 4;
    scale_rows64<<<(N_NODES * 64 + 255) / 256, 256, 0, stream>>>(x, dis, bufA);
    csr_agg<64><<<aggGrid, 256, 0, stream>>>(bufA, rowptr, csrsrc, dis, bufB);
    gemm(bufB, G1W, G1b, dis, bufA, N_NODES, 64, 128, 2, 1);      // Hs1 = dis*elu(.)
    csr_agg<128><<<aggGrid, 256, 0, stream>>>(bufA, rowptr, csrsrc, dis, bufB);
    gemm(bufB, G2W, G2b, dis, bufA, N_NODES, 128, 128, 2, 1);     // Hs2
    csr_agg<128><<<aggGrid, 256, 0, stream>>>(bufA, rowptr, csrsrc, dis, bufB);
    gemm(bufB, G3W, G3b, nullptr, bufA, N_NODES, 128, 256, 0, 0); // h3 [100k,256]

    // ---- per-graph mean pool ----
    hipMemsetAsync(pooled, 0, (BATCH * 256 + BATCH) * 4, stream);
    pool_chunk<<<(N_NODES + POOL_CHUNK - 1) / POOL_CHUNK, 256, 0, stream>>>(bufA, batch, pooled, counts);

    // ---- fused tail: concat + final GEMM + heads (pool divide folded in) ----
    final_fused<<<BATCH, 256, 0, stream>>>(fusedb, pooled, counts, Wff, bff, Wb, bb, Wa, ba, (float*)d_out);
}

// Round 4
// 718.849 us; speedup vs baseline: 17.2631x; 2.0279x over previous
//
#include <hip/hip_runtime.h>
#include <hip/hip_bf16.h>

#define N_NODES 100000
#define NPAD    100096          // 782 * 128
#define N_EDGES 1600000
#define BATCH   256
#define HDIM    512

typedef unsigned short u16;
typedef __attribute__((ext_vector_type(8))) short bf16x8;
typedef __attribute__((ext_vector_type(4))) float f32x4;

__device__ __forceinline__ float bf2f(u16 u) {
    union { unsigned i; float f; } v; v.i = ((unsigned)u) << 16; return v.f;
}
__device__ __forceinline__ u16 f2bf(float f) {
    __hip_bfloat16 h = __float2bfloat16(f);
    return *reinterpret_cast<u16*>(&h);
}

// ============ MFMA GEMM: C[M,N](bf16) = act(A[M,K](bf16) @ W[K,N]) ==========
// A: [M][K] bf16 row-major. Wt: [N][K] bf16 (W transposed). Single K-stage
// (BK = K <= 128). 128x128 tile, 4 waves (2x2), each 64x64 = 4x4 frags of
// 16x16x32. LDS staged via global_load_lds w=16 with pre-swizzled source
// (cb ^= (row&7)<<4) so ds_read_b128 is 2-way-conflict-free.
// ACT: 0 none, 2 elu. SCALE: multiply by dis[row] after act.
template<int K, int ACT, int SCALE>
__global__ __launch_bounds__(256) void gemm_mfma(
        const u16* __restrict__ A, const u16* __restrict__ Wt,
        const float* __restrict__ bias, const float* __restrict__ dis,
        u16* __restrict__ C, int N) {
    constexpr int RB = K * 2;                 // row bytes
    __shared__ u16 As[128 * K];
    __shared__ u16 Bs[128 * K];
    const int tid  = threadIdx.x;
    const int lane = tid & 63;
    const int w    = tid >> 6;
    const int wr   = w >> 1, wc = w & 1;      // 2x2 wave grid
    const int row0 = blockIdx.y * 128;
    const int col0 = blockIdx.x * 128;

    // ---- stage A and B tiles (swizzled global source, linear LDS dest) ----
    constexpr int WB     = 128 * RB / 4;      // bytes per wave per tile
    constexpr int PASSES = WB / 1024;         // 4 (K=64) or 8 (K=128)
    const size_t Abase = (size_t)row0 * K;
    const size_t Bbase = (size_t)col0 * K;
    #pragma unroll
    for (int p = 0; p < PASSES; ++p) {
        int Lb  = w * WB + p * 1024;          // wave-uniform LDS base (bytes)
        int L   = Lb + lane * 16;             // this lane's tile byte offset
        int row = L / RB;
        int cb  = L % RB;
        int scb = cb ^ ((row & 7) << 4);      // pre-swizzle the SOURCE
        const u16* ga = A  + Abase + (size_t)row * K + (scb >> 1);
        const u16* gb = Wt + Bbase + (size_t)row * K + (scb >> 1);
        __builtin_amdgcn_global_load_lds((const __attribute__((address_space(1))) void*)ga,
            (__attribute__((address_space(3))) void*)&As[Lb >> 1], 16, 0, 0);
        __builtin_amdgcn_global_load_lds((const __attribute__((address_space(1))) void*)gb,
            (__attribute__((address_space(3))) void*)&Bs[Lb >> 1], 16, 0, 0);
    }
    asm volatile("s_waitcnt vmcnt(0)" ::: "memory");
    __syncthreads();

    // ---- MFMA: acc[m][n] over K ----
    const int rl = lane & 15;                 // row within fragment
    const int kg = lane >> 4;                 // k-group (0..3)
    f32x4 acc[4][4] = {};
    #pragma unroll
    for (int s = 0; s < K / 32; ++s) {
        bf16x8 af[4], bg[4];
        #pragma unroll
        for (int m = 0; m < 4; ++m) {
            int row = wr * 64 + m * 16 + rl;
            int cb  = s * 64 + kg * 16;
            int scb = cb ^ ((row & 7) << 4);
            af[m] = *(const bf16x8*)&As[(row * RB + scb) >> 1];
        }
        #pragma unroll
        for (int n = 0; n < 4; ++n) {
            int row = wc * 64 + n * 16 + rl;
            int cb  = s * 64 + kg * 16;
            int scb = cb ^ ((row & 7) << 4);
            bg[n] = *(const bf16x8*)&Bs[(row * RB + scb) >> 1];
        }
        #pragma unroll
        for (int m = 0; m < 4; ++m)
            #pragma unroll
            for (int n = 0; n < 4; ++n)
                acc[m][n] = __builtin_amdgcn_mfma_f32_16x16x32_bf16(af[m], bg[n], acc[m][n], 0, 0, 0);
    }

    // ---- epilogue: bias + act + dis-scale, store bf16 ----
    // C/D layout: col = lane&15, row = (lane>>4)*4 + reg  [m89-verified]
    #pragma unroll
    for (int m = 0; m < 4; ++m) {
        #pragma unroll
        for (int r = 0; r < 4; ++r) {
            int grow = row0 + wr * 64 + m * 16 + kg * 4 + r;
            float ds = SCALE ? dis[grow] : 1.f;
            #pragma unroll
            for (int n = 0; n < 4; ++n) {
                int gcol = col0 + wc * 64 + n * 16 + rl;
                float v = acc[m][n][r] + bias[gcol];
                if (ACT == 2) v = v > 0.f ? v : expm1f(v);
                C[(size_t)grow * N + gcol] = f2bf(v * ds);
            }
        }
    }
}

// ============ W[K][N] f32 -> Wt[N][K] bf16 ============
__global__ void transpose_w(const float* __restrict__ W, u16* __restrict__ Wt,
                            int K, int N) {
    int t = blockIdx.x * 256 + threadIdx.x;
    if (t >= K * N) return;
    int k = t / N, n = t % N;
    Wt[(size_t)n * K + k] = f2bf(W[t]);
}

// ================= fused front-end: one block per batch row ==================
__global__ void frontend_fused(const float* __restrict__ video,
                               const float* __restrict__ Wv,  const float* __restrict__ bv,
                               const float* __restrict__ Wva, const float* __restrict__ bva,
                               const float* __restrict__ Wo,  const float* __restrict__ bo,
                               const float* __restrict__ Wf,  const float* __restrict__ bf,
                               float* __restrict__ fusedb) {
    __shared__ float vin[512], venc[512], vattn[512], ta[512];
    const int b = blockIdx.x, tid = threadIdx.x;
    vin[tid] = video[b * 512 + tid];
    vin[tid + 256] = video[b * 512 + 256 + tid];
    __syncthreads();
    {
        float a0 = bv[tid], a1 = bv[tid + 256];
        #pragma unroll 8
        for (int k = 0; k < 512; ++k) {
            float xv = vin[k];
            a0 += xv * Wv[k * 512 + tid];
            a1 += xv * Wv[k * 512 + tid + 256];
        }
        venc[tid] = fmaxf(a0, 0.f);
        venc[tid + 256] = fmaxf(a1, 0.f);
    }
    __syncthreads();
    {
        float a0 = bva[tid], a1 = bva[tid + 256];
        #pragma unroll 8
        for (int k = 0; k < 512; ++k) {
            float xv = venc[k];
            a0 += xv * Wva[k * 512 + tid];
            a1 += xv * Wva[k * 512 + tid + 256];
        }
        vattn[tid] = a0;
        vattn[tid + 256] = a1;
    }
    __syncthreads();
    {
        float a0 = bo[tid], a1 = bo[tid + 256];
        #pragma unroll 8
        for (int k = 0; k < 512; ++k) {
            float xv = vattn[k];
            a0 += xv * Wo[k * 512 + tid];
            a1 += xv * Wo[k * 512 + tid + 256];
        }
        ta[tid] = a0;
        ta[tid + 256] = a1;
    }
    __syncthreads();
    {
        float a0 = bf[tid], a1 = bf[tid + 256];
        #pragma unroll 8
        for (int k = 0; k < 512; ++k) {
            float xv = ta[k];
            a0 += xv * Wf[k * 512 + tid];
            a1 += xv * Wf[k * 512 + tid + 256];
        }
        #pragma unroll 8
        for (int k = 0; k < 512; ++k) {
            float xv = venc[k];
            a0 += xv * Wf[(512 + k) * 512 + tid];
            a1 += xv * Wf[(512 + k) * 512 + tid + 256];
        }
        fusedb[b * 512 + tid] = fmaxf(a0, 0.f);
        fusedb[b * 512 + tid + 256] = fmaxf(a1, 0.f);
    }
}

// ====== fused tail: final = relu([fused|pooled/cnt]@Wff+bff); 2 heads ========
__global__ void final_fused(const float* __restrict__ fusedb,
                            const float* __restrict__ pooled, const float* __restrict__ counts,
                            const float* __restrict__ Wff, const float* __restrict__ bff,
                            const float* __restrict__ Wb,  const float* __restrict__ bb,
                            const float* __restrict__ Wa,  const float* __restrict__ ba,
                            float* __restrict__ out) {
    __shared__ float cat[768], fin[512];
    __shared__ float rd[4][4];
    const int b = blockIdx.x, tid = threadIdx.x;
    cat[tid] = fusedb[b * 512 + tid];
    cat[tid + 256] = fusedb[b * 512 + 256 + tid];
    float inv = 1.f / counts[b];
    cat[512 + tid] = pooled[b * 256 + tid] * inv;
    __syncthreads();
    {
        float a0 = bff[tid], a1 = bff[tid + 256];
        #pragma unroll 8
        for (int k = 0; k < 768; ++k) {
            float xv = cat[k];
            a0 += xv * Wff[k * 512 + tid];
            a1 += xv * Wff[k * 512 + tid + 256];
        }
        fin[tid] = fmaxf(a0, 0.f);
        fin[tid + 256] = fmaxf(a1, 0.f);
    }
    __syncthreads();
    float z0 = 0.f, z1 = 0.f, y0 = 0.f, y1 = 0.f;
    for (int k = tid; k < 512; k += 256) {
        float f = fin[k];
        z0 += f * Wb[2 * k];
        z1 += f * Wb[2 * k + 1];
        y0 += f * Wa[2 * k];
        y1 += f * Wa[2 * k + 1];
    }
    #pragma unroll
    for (int off = 32; off > 0; off >>= 1) {
        z0 += __shfl_down(z0, off);
        z1 += __shfl_down(z1, off);
        y0 += __shfl_down(y0, off);
        y1 += __shfl_down(y1, off);
    }
    int ww = tid >> 6;
    if ((tid & 63) == 0) { rd[ww][0] = z0; rd[ww][1] = z1; rd[ww][2] = y0; rd[ww][3] = y1; }
    __syncthreads();
    if (tid == 0) {
        float Z0 = rd[0][0] + rd[1][0] + rd[2][0] + rd[3][0] + bb[0];
        float Z1 = rd[0][1] + rd[1][1] + rd[2][1] + rd[3][1] + bb[1];
        float Y0 = rd[0][2] + rd[1][2] + rd[2][2] + rd[3][2] + ba[0];
        float Y1 = rd[0][3] + rd[1][3] + rd[2][3] + rd[3][3] + ba[1];
        float m = fmaxf(Z0, Z1);
        float l = m + logf(expf(Z0 - m) + expf(Z1 - m));
        out[b * 2 + 0] = Z0 - l;
        out[b * 2 + 1] = Z1 - l;
        float m2 = fmaxf(Y0, Y1);
        float l2 = m2 + logf(expf(Y0 - m2) + expf(Y1 - m2));
        out[512 + b * 2 + 0] = Y0 - l2;
        out[512 + b * 2 + 1] = Y1 - l2;
    }
}

// ================= degree / dis =================
__global__ void deg_count(const int* __restrict__ dst, int* __restrict__ deg, int E) {
    int i = blockIdx.x * blockDim.x + threadIdx.x;
    if (i < E) atomicAdd(&deg[dst[i]], 1);
}

__global__ void make_dis(const int* __restrict__ deg, float* __restrict__ dis, int n) {
    int i = blockIdx.x * blockDim.x + threadIdx.x;
    if (i < n) dis[i] = rsqrtf((float)deg[i] + 1.f);
}

// ================= exclusive scan (1024 elems/block) =================
__global__ void scan1(const int* __restrict__ in, int* __restrict__ out,
                      int* __restrict__ bsum, int n) {
    __shared__ int ts[256];
    const int tid = threadIdx.x;
    const int base = blockIdx.x * 1024;
    int v[4];
    #pragma unroll
    for (int i = 0; i < 4; ++i) {
        int idx = base + tid * 4 + i;
        v[i] = (idx < n) ? in[idx] : 0;
    }
    ts[tid] = v[0] + v[1] + v[2] + v[3];
    __syncthreads();
    for (int off = 1; off < 256; off <<= 1) {
        int val = (tid >= off) ? ts[tid - off] : 0;
        __syncthreads();
        ts[tid] += val;
        __syncthreads();
    }
    int run = (tid == 0) ? 0 : ts[tid - 1];
    if (tid == 255) bsum[blockIdx.x] = ts[255];
    #pragma unroll
    for (int i = 0; i < 4; ++i) {
        int idx = base + tid * 4 + i;
        if (idx < n) out[idx] = run;
        run += v[i];
    }
}

__global__ void scan2(int* __restrict__ bsum, int nb) {
    if (threadIdx.x == 0 && blockIdx.x == 0) {
        int run = 0;
        for (int i = 0; i < nb; ++i) { int t = bsum[i]; bsum[i] = run; run += t; }
    }
}

__global__ void scan3(int* __restrict__ out, const int* __restrict__ bsum, int n, int total) {
    int idx = blockIdx.x * 1024 + threadIdx.x * 4;
    int add = bsum[blockIdx.x];
    #pragma unroll
    for (int i = 0; i < 4; ++i)
        if (idx + i < n) out[idx + i] += add;
    if (blockIdx.x == 0 && threadIdx.x == 0) out[n] = total;
}

// ================= CSR scatter =================
__global__ void csr_scatter(const int* __restrict__ srcE, const int* __restrict__ dstE,
                            const int* __restrict__ rowptr, int* __restrict__ cursor,
                            int* __restrict__ csr_src, int E) {
    int e = blockIdx.x * blockDim.x + threadIdx.x;
    if (e >= E) return;
    int d = dstE[e];
    int pos = rowptr[d] + atomicAdd(&cursor[d], 1);
    csr_src[pos] = srcE[e];
}

// ================= Hs0 = bf16(dis * x)  (64 cols) =================
__global__ void scale_rows64_bf16(const float* __restrict__ x, const float* __restrict__ dis,
                                  u16* __restrict__ out) {
    int t = blockIdx.x * blockDim.x + threadIdx.x;
    if (t >= N_NODES * 64) return;
    out[t] = f2bf(x[t] * dis[t >> 6]);
}

// ===== CSR aggregate (bf16): out[d] = bf16( dis[d]*(Hs[d] + sum Hs[src]) ) ==
// One wave per node. Each lane owns 4 channels (ushort4 = 8B). G = 256/C edge
// slots run concurrently; cross-slot reduce via shfl_xor.
template<int C>
__global__ void csr_agg_bf16(const u16* __restrict__ Hs, const int* __restrict__ rowptr,
                             const int* __restrict__ csr_src, const float* __restrict__ dis,
                             u16* __restrict__ out) {
    constexpr int LPG = C / 4;        // lanes per row
    constexpr int G   = 64 / LPG;     // concurrent edges
    int node = blockIdx.x * 4 + (threadIdx.x >> 6);
    if (node >= N_NODES) return;
    int lane = threadIdx.x & 63;
    int g  = lane / LPG;
    int cl = lane % LPG;              // channels cl*4 .. cl*4+3
    int s0 = rowptr[node], s1 = rowptr[node + 1];
    float ax = 0.f, ay = 0.f, az = 0.f, aw = 0.f;
    if (g == 0) {
        ushort4 v = *(const ushort4*)&Hs[(size_t)node * C + cl * 4];
        ax = bf2f(v.x); ay = bf2f(v.y); az = bf2f(v.z); aw = bf2f(v.w);
    }
    for (int e = s0 + g; e < s1; e += G) {
        int s = csr_src[e];
        ushort4 v = *(const ushort4*)&Hs[(size_t)s * C + cl * 4];
        ax += bf2f(v.x); ay += bf2f(v.y); az += bf2f(v.z); aw += bf2f(v.w);
    }
    #pragma unroll
    for (int m = LPG; m < 64; m <<= 1) {
        ax += __shfl_xor(ax, m);
        ay += __shfl_xor(ay, m);
        az += __shfl_xor(az, m);
        aw += __shfl_xor(aw, m);
    }
    if (g == 0) {
        float dd = dis[node];
        ushort4 o;
        o.x = f2bf(ax * dd); o.y = f2bf(ay * dd);
        o.z = f2bf(az * dd); o.w = f2bf(aw * dd);
        *(ushort4*)&out[(size_t)node * C + cl * 4] = o;
    }
}

// ================= chunked mean pool (batch_idx is sorted), bf16 in =========
#define POOL_CHUNK 100
__global__ void pool_chunk(const u16* __restrict__ h, const int* __restrict__ batch,
                           float* __restrict__ pooled, float* __restrict__ counts) {
    int c = threadIdx.x;
    int i0 = blockIdx.x * POOL_CHUNK;
    int i1 = min(i0 + POOL_CHUNK, N_NODES);
    float acc = 0.f;
    int cur = batch[i0], cnt = 0;
    for (int i = i0; i < i1; ++i) {
        int b = batch[i];
        if (b != cur) {
            atomicAdd(&pooled[cur * 256 + c], acc);
            if (c == 0) atomicAdd(&counts[cur], (float)cnt);
            acc = 0.f; cnt = 0; cur = b;
        }
        acc += bf2f(h[(size_t)i * 256 + c]);
        cnt++;
    }
    atomicAdd(&pooled[cur * 256 + c], acc);
    if (c == 0) atomicAdd(&counts[cur], (float)cnt);
}

extern "C" void kernel_launch(void* const* d_in, const int* in_sizes, int n_in,
                              void* d_out, int out_size, void* d_ws, size_t ws_size,
                              hipStream_t stream) {
    // ---- inputs (setup_inputs order) ----
    const float* video = (const float*)d_in[1];
    const float* x     = (const float*)d_in[2];
    const int*   eidx  = (const int*)d_in[3];
    const int*   batch = (const int*)d_in[4];
    // text branch + Wq/Wk are dead: seq-len-1 softmax == 1 -> attn = v.
    const float* Wv  = (const float*)d_in[7],  *bv  = (const float*)d_in[8];
    const float* Wva = (const float*)d_in[13], *bva = (const float*)d_in[14];
    const float* Wo  = (const float*)d_in[15], *bo  = (const float*)d_in[16];
    const float* Wf  = (const float*)d_in[17], *bf  = (const float*)d_in[18];
    const float* G1W = (const float*)d_in[19], *G1b = (const float*)d_in[20];
    const float* G2W = (const float*)d_in[21], *G2b = (const float*)d_in[22];
    const float* G3W = (const float*)d_in[23], *G3b = (const float*)d_in[24];
    const float* Wff = (const float*)d_in[25], *bff = (const float*)d_in[26];
    const float* Wb  = (const float*)d_in[27], *bb  = (const float*)d_in[28];
    const float* Wa  = (const float*)d_in[29], *ba  = (const float*)d_in[30];
    const int* srcE = eidx;
    const int* dstE = eidx + N_EDGES;

    // ---- workspace layout ----
    char* wsc = (char*)d_ws;
    size_t off = 0;
    auto alloc = [&](size_t bytes) { char* p = wsc + off; off += (bytes + 255) & ~(size_t)255; return p; };
    u16*   bufA   = (u16*)  alloc((size_t)NPAD * 256 * 2);   // Hs / h3 (bf16)
    u16*   bufB   = (u16*)  alloc((size_t)NPAD * 128 * 2);   // agg outputs (bf16)
    float* dis    = (float*)alloc(NPAD * 4);
    int*   deg    = (int*)  alloc(NPAD * 4);
    int*   rowptr = (int*)  alloc((N_NODES + 1) * 4);
    int*   cursor = (int*)  alloc(N_NODES * 4);
    int*   csrsrc = (int*)  alloc((size_t)N_EDGES * 4);
    int*   bsum   = (int*)  alloc(128 * 4);
    u16*   g1wt   = (u16*)  alloc(128 * 64 * 2);
    u16*   g2wt   = (u16*)  alloc(128 * 128 * 2);
    u16*   g3wt   = (u16*)  alloc(256 * 128 * 2);
    float* fusedb = (float*)alloc(BATCH * 512 * 4);
    float* pooled = (float*)alloc(BATCH * 256 * 4);
    float* counts = (float*)alloc(BATCH * 4);

    const int NB = (N_NODES + 1023) / 1024;   // 98
    const int aggGrid = (N_NODES + 3) / 4;

    // ---- degree, dis, CSR ----
    hipMemsetAsync(deg, 0, NPAD * 4, stream);
    hipMemsetAsync(cursor, 0, N_NODES * 4, stream);
    deg_count<<<(N_EDGES + 255) / 256, 256, 0, stream>>>(dstE, deg, N_EDGES);
    make_dis<<<(NPAD + 255) / 256, 256, 0, stream>>>(deg, dis, NPAD);
    scan1<<<NB, 256, 0, stream>>>(deg, rowptr, bsum, N_NODES);
    scan2<<<1, 64, 0, stream>>>(bsum, NB);
    scan3<<<NB, 256, 0, stream>>>(rowptr, bsum, N_NODES, N_EDGES);
    csr_scatter<<<(N_EDGES + 255) / 256, 256, 0, stream>>>(srcE, dstE, rowptr, cursor, csrsrc, N_EDGES);

    // ---- weight transposes to bf16 (tiny) ----
    transpose_w<<<(64 * 128 + 255) / 256, 256, 0, stream>>>(G1W, g1wt, 64, 128);
    transpose_w<<<(128 * 128 + 255) / 256, 256, 0, stream>>>(G2W, g2wt, 128, 128);
    transpose_w<<<(128 * 256 + 255) / 256, 256, 0, stream>>>(G3W, g3wt, 128, 256);

    // ---- fused front-end ----
    frontend_fused<<<BATCH, 256, 0, stream>>>(video, Wv, bv, Wva, bva, Wo, bo, Wf, bf, fusedb);

    // ---- GCN stack: aggregate-first, bf16 features, MFMA GEMMs ----
    scale_rows64_bf16<<<(N_NODES * 64 + 255) / 256, 256, 0, stream>>>(x, dis, bufA);
    csr_agg_bf16<64><<<aggGrid, 256, 0, stream>>>(bufA, rowptr, csrsrc, dis, bufB);
    gemm_mfma<64, 2, 1><<<dim3(1, NPAD / 128), 256, 0, stream>>>(bufB, g1wt, G1b, dis, bufA, 128);
    csr_agg_bf16<128><<<aggGrid, 256, 0, stream>>>(bufA, rowptr, csrsrc, dis, bufB);
    gemm_mfma<128, 2, 1><<<dim3(1, NPAD / 128), 256, 0, stream>>>(bufB, g2wt, G2b, dis, bufA, 128);
    csr_agg_bf16<128><<<aggGrid, 256, 0, stream>>>(bufA, rowptr, csrsrc, dis, bufB);
    gemm_mfma<128, 0, 0><<<dim3(2, NPAD / 128), 256, 0, stream>>>(bufB, g3wt, G3b, nullptr, bufA, 256);

    // ---- per-graph mean pool ----
    hipMemsetAsync(pooled, 0, (BATCH * 256 + BATCH) * 4, stream);
    pool_chunk<<<(N_NODES + POOL_CHUNK - 1) / POOL_CHUNK, 256, 0, stream>>>(bufA, batch, pooled, counts);

    // ---- fused tail ----
    final_fused<<<BATCH, 256, 0, stream>>>(fusedb, pooled, counts, Wff, bff, Wb, bb, Wa, ba, (float*)d_out);
}

// Round 5
// 596.158 us; speedup vs baseline: 20.8159x; 1.2058x over previous
//
#include <hip/hip_runtime.h>
#include <hip/hip_bf16.h>

#define N_NODES 100000
#define NPAD    100096          // 782 * 128
#define N_EDGES 1600000
#define BATCH   256
#define HDIM    512

typedef unsigned short u16;
typedef __attribute__((ext_vector_type(8))) short bf16x8;
typedef __attribute__((ext_vector_type(8))) unsigned short u16x8;
typedef __attribute__((ext_vector_type(4))) float f32x4;

__device__ __forceinline__ float bf2f(u16 u) {
    union { unsigned i; float f; } v; v.i = ((unsigned)u) << 16; return v.f;
}
__device__ __forceinline__ u16 f2bf(float f) {
    __hip_bfloat16 h = __float2bfloat16(f);
    return *reinterpret_cast<u16*>(&h);
}

// ============ MFMA GEMM (node path): C = act(A[M,K]@W) , K<=128, 1 stage =====
// A: [M][K] bf16. Wt: [N][K] bf16. 128x128 tile, 4 waves 2x2, 4x4 frags of
// 16x16x32. LDS via global_load_lds w=16, pre-swizzled source (rule 21).
// ACT: 0 none, 2 elu. SCALE: multiply by dis[row] after act.
template<int K, int ACT, int SCALE>
__global__ __launch_bounds__(256) void gemm_mfma(
        const u16* __restrict__ A, const u16* __restrict__ Wt,
        const float* __restrict__ bias, const float* __restrict__ dis,
        u16* __restrict__ C, int N) {
    constexpr int RB = K * 2;                 // row bytes
    __shared__ u16 As[128 * K];
    __shared__ u16 Bs[128 * K];
    const int tid  = threadIdx.x;
    const int lane = tid & 63;
    const int w    = tid >> 6;
    const int wr   = w >> 1, wc = w & 1;
    const int row0 = blockIdx.y * 128;
    const int col0 = blockIdx.x * 128;

    constexpr int WB     = 128 * RB / 4;
    constexpr int PASSES = WB / 1024;
    const size_t Abase = (size_t)row0 * K;
    const size_t Bbase = (size_t)col0 * K;
    #pragma unroll
    for (int p = 0; p < PASSES; ++p) {
        int Lb  = w * WB + p * 1024;
        int L   = Lb + lane * 16;
        int row = L / RB;
        int cb  = L % RB;
        int scb = cb ^ ((row & 7) << 4);
        const u16* ga = A  + Abase + (size_t)row * K + (scb >> 1);
        const u16* gb = Wt + Bbase + (size_t)row * K + (scb >> 1);
        __builtin_amdgcn_global_load_lds((const __attribute__((address_space(1))) void*)ga,
            (__attribute__((address_space(3))) void*)&As[Lb >> 1], 16, 0, 0);
        __builtin_amdgcn_global_load_lds((const __attribute__((address_space(1))) void*)gb,
            (__attribute__((address_space(3))) void*)&Bs[Lb >> 1], 16, 0, 0);
    }
    asm volatile("s_waitcnt vmcnt(0)" ::: "memory");
    __syncthreads();

    const int rl = lane & 15;
    const int kg = lane >> 4;
    f32x4 acc[4][4] = {};
    #pragma unroll
    for (int s = 0; s < K / 32; ++s) {
        bf16x8 af[4], bg[4];
        #pragma unroll
        for (int m = 0; m < 4; ++m) {
            int row = wr * 64 + m * 16 + rl;
            int cb  = s * 64 + kg * 16;
            int scb = cb ^ ((row & 7) << 4);
            af[m] = *(const bf16x8*)&As[(row * RB + scb) >> 1];
        }
        #pragma unroll
        for (int n = 0; n < 4; ++n) {
            int row = wc * 64 + n * 16 + rl;
            int cb  = s * 64 + kg * 16;
            int scb = cb ^ ((row & 7) << 4);
            bg[n] = *(const bf16x8*)&Bs[(row * RB + scb) >> 1];
        }
        #pragma unroll
        for (int m = 0; m < 4; ++m)
            #pragma unroll
            for (int n = 0; n < 4; ++n)
                acc[m][n] = __builtin_amdgcn_mfma_f32_16x16x32_bf16(af[m], bg[n], acc[m][n], 0, 0, 0);
    }

    #pragma unroll
    for (int m = 0; m < 4; ++m) {
        #pragma unroll
        for (int r = 0; r < 4; ++r) {
            int grow = row0 + wr * 64 + m * 16 + kg * 4 + r;
            float ds = SCALE ? dis[grow] : 1.f;
            #pragma unroll
            for (int n = 0; n < 4; ++n) {
                int gcol = col0 + wc * 64 + n * 16 + rl;
                float v = acc[m][n][r] + bias[gcol];
                if (ACT == 2) v = v > 0.f ? v : expm1f(v);
                C[(size_t)grow * N + gcol] = f2bf(v * ds);
            }
        }
    }
}

// ======== MFMA GEMM (front-end): K-loop (BK=64), runtime lda/ldc =============
// ACT: 0 none, 1 relu.
template<int ACT>
__global__ __launch_bounds__(256) void gemm_loop(
        const u16* __restrict__ A, const u16* __restrict__ Wt,
        const float* __restrict__ bias, u16* __restrict__ C,
        int N, int K, int lda, int ldc) {
    __shared__ u16 As[128 * 64];
    __shared__ u16 Bs[128 * 64];
    const int tid  = threadIdx.x;
    const int lane = tid & 63;
    const int w    = tid >> 6;
    const int wr   = w >> 1, wc = w & 1;
    const int row0 = blockIdx.y * 128;
    const int col0 = blockIdx.x * 128;
    const int rl = lane & 15;
    const int kg = lane >> 4;
    f32x4 acc[4][4] = {};

    for (int k0 = 0; k0 < K; k0 += 64) {
        #pragma unroll
        for (int p = 0; p < 4; ++p) {
            int Lb  = w * 4096 + p * 1024;
            int L   = Lb + lane * 16;
            int row = L >> 7;               // 128 B per row-chunk
            int cb  = L & 127;
            int scb = cb ^ ((row & 7) << 4);
            const u16* ga = A  + (size_t)(row0 + row) * lda + k0 + (scb >> 1);
            const u16* gb = Wt + (size_t)(col0 + row) * K   + k0 + (scb >> 1);
            __builtin_amdgcn_global_load_lds((const __attribute__((address_space(1))) void*)ga,
                (__attribute__((address_space(3))) void*)&As[Lb >> 1], 16, 0, 0);
            __builtin_amdgcn_global_load_lds((const __attribute__((address_space(1))) void*)gb,
                (__attribute__((address_space(3))) void*)&Bs[Lb >> 1], 16, 0, 0);
        }
        asm volatile("s_waitcnt vmcnt(0)" ::: "memory");
        __syncthreads();
        #pragma unroll
        for (int s = 0; s < 2; ++s) {
            bf16x8 af[4], bg[4];
            #pragma unroll
            for (int m = 0; m < 4; ++m) {
                int row = wr * 64 + m * 16 + rl;
                int cb  = s * 64 + kg * 16;
                int scb = cb ^ ((row & 7) << 4);
                af[m] = *(const bf16x8*)&As[(row * 128 + scb) >> 1];
            }
            #pragma unroll
            for (int n = 0; n < 4; ++n) {
                int row = wc * 64 + n * 16 + rl;
                int cb  = s * 64 + kg * 16;
                int scb = cb ^ ((row & 7) << 4);
                bg[n] = *(const bf16x8*)&Bs[(row * 128 + scb) >> 1];
            }
            #pragma unroll
            for (int m = 0; m < 4; ++m)
                #pragma unroll
                for (int n = 0; n < 4; ++n)
                    acc[m][n] = __builtin_amdgcn_mfma_f32_16x16x32_bf16(af[m], bg[n], acc[m][n], 0, 0, 0);
        }
        __syncthreads();
    }

    #pragma unroll
    for (int m = 0; m < 4; ++m) {
        #pragma unroll
        for (int r = 0; r < 4; ++r) {
            int grow = row0 + wr * 64 + m * 16 + kg * 4 + r;
            #pragma unroll
            for (int n = 0; n < 4; ++n) {
                int gcol = col0 + wc * 64 + n * 16 + rl;
                float v = acc[m][n][r] + bias[gcol];
                if (ACT == 1) v = fmaxf(v, 0.f);
                C[(size_t)grow * ldc + gcol] = f2bf(v);
            }
        }
    }
}

// ============ W[K][N] f32 -> Wt[N][K] bf16 (output-coalesced) ============
__global__ void transpose_w(const float* __restrict__ W, u16* __restrict__ Wt,
                            int K, int N) {
    int t = blockIdx.x * 256 + threadIdx.x;
    if (t >= K * N) return;
    int n = t / K, k = t % K;
    Wt[t] = f2bf(W[(size_t)k * N + n]);
}

__global__ void f32_to_bf16(const float* __restrict__ in, u16* __restrict__ out, int n) {
    int t = blockIdx.x * 256 + threadIdx.x;
    if (t < n) out[t] = f2bf(in[t]);
}

// ====== fused tail: final = relu([fused|pooled/cnt]@Wff+bff); 2 heads ========
__global__ void final_fused(const u16* __restrict__ fusedb,
                            const float* __restrict__ pooled, const float* __restrict__ counts,
                            const float* __restrict__ Wff, const float* __restrict__ bff,
                            const float* __restrict__ Wb,  const float* __restrict__ bb,
                            const float* __restrict__ Wa,  const float* __restrict__ ba,
                            float* __restrict__ out) {
    __shared__ float cat[768], fin[512];
    __shared__ float rd[4][4];
    const int b = blockIdx.x, tid = threadIdx.x;
    cat[tid] = bf2f(fusedb[b * 512 + tid]);
    cat[tid + 256] = bf2f(fusedb[b * 512 + 256 + tid]);
    float inv = 1.f / counts[b];
    cat[512 + tid] = pooled[b * 256 + tid] * inv;
    __syncthreads();
    {
        float a0 = bff[tid], a1 = bff[tid + 256];
        #pragma unroll 8
        for (int k = 0; k < 768; ++k) {
            float xv = cat[k];
            a0 += xv * Wff[k * 512 + tid];
            a1 += xv * Wff[k * 512 + tid + 256];
        }
        fin[tid] = fmaxf(a0, 0.f);
        fin[tid + 256] = fmaxf(a1, 0.f);
    }
    __syncthreads();
    float z0 = 0.f, z1 = 0.f, y0 = 0.f, y1 = 0.f;
    for (int k = tid; k < 512; k += 256) {
        float f = fin[k];
        z0 += f * Wb[2 * k];
        z1 += f * Wb[2 * k + 1];
        y0 += f * Wa[2 * k];
        y1 += f * Wa[2 * k + 1];
    }
    #pragma unroll
    for (int off = 32; off > 0; off >>= 1) {
        z0 += __shfl_down(z0, off);
        z1 += __shfl_down(z1, off);
        y0 += __shfl_down(y0, off);
        y1 += __shfl_down(y1, off);
    }
    int ww = tid >> 6;
    if ((tid & 63) == 0) { rd[ww][0] = z0; rd[ww][1] = z1; rd[ww][2] = y0; rd[ww][3] = y1; }
    __syncthreads();
    if (tid == 0) {
        float Z0 = rd[0][0] + rd[1][0] + rd[2][0] + rd[3][0] + bb[0];
        float Z1 = rd[0][1] + rd[1][1] + rd[2][1] + rd[3][1] + bb[1];
        float Y0 = rd[0][2] + rd[1][2] + rd[2][2] + rd[3][2] + ba[0];
        float Y1 = rd[0][3] + rd[1][3] + rd[2][3] + rd[3][3] + ba[1];
        float m = fmaxf(Z0, Z1);
        float l = m + logf(expf(Z0 - m) + expf(Z1 - m));
        out[b * 2 + 0] = Z0 - l;
        out[b * 2 + 1] = Z1 - l;
        float m2 = fmaxf(Y0, Y1);
        float l2 = m2 + logf(expf(Y0 - m2) + expf(Y1 - m2));
        out[512 + b * 2 + 0] = Y0 - l2;
        out[512 + b * 2 + 1] = Y1 - l2;
    }
}

// ================= degree / dis =================
__global__ void deg_count(const int* __restrict__ dst, int* __restrict__ deg, int E) {
    int i = blockIdx.x * blockDim.x + threadIdx.x;
    if (i < E) atomicAdd(&deg[dst[i]], 1);
}

__global__ void make_dis(const int* __restrict__ deg, float* __restrict__ dis, int n) {
    int i = blockIdx.x * blockDim.x + threadIdx.x;
    if (i < n) dis[i] = rsqrtf((float)deg[i] + 1.f);
}

// ================= exclusive scan (1024 elems/block) =================
__global__ void scan1(const int* __restrict__ in, int* __restrict__ out,
                      int* __restrict__ bsum, int n) {
    __shared__ int ts[256];
    const int tid = threadIdx.x;
    const int base = blockIdx.x * 1024;
    int v[4];
    #pragma unroll
    for (int i = 0; i < 4; ++i) {
        int idx = base + tid * 4 + i;
        v[i] = (idx < n) ? in[idx] : 0;
    }
    ts[tid] = v[0] + v[1] + v[2] + v[3];
    __syncthreads();
    for (int off = 1; off < 256; off <<= 1) {
        int val = (tid >= off) ? ts[tid - off] : 0;
        __syncthreads();
        ts[tid] += val;
        __syncthreads();
    }
    int run = (tid == 0) ? 0 : ts[tid - 1];
    if (tid == 255) bsum[blockIdx.x] = ts[255];
    #pragma unroll
    for (int i = 0; i < 4; ++i) {
        int idx = base + tid * 4 + i;
        if (idx < n) out[idx] = run;
        run += v[i];
    }
}

__global__ void scan2(int* __restrict__ bsum, int nb) {
    if (threadIdx.x == 0 && blockIdx.x == 0) {
        int run = 0;
        for (int i = 0; i < nb; ++i) { int t = bsum[i]; bsum[i] = run; run += t; }
    }
}

__global__ void scan3(int* __restrict__ out, const int* __restrict__ bsum, int n, int total) {
    int idx = blockIdx.x * 1024 + threadIdx.x * 4;
    int add = bsum[blockIdx.x];
    #pragma unroll
    for (int i = 0; i < 4; ++i)
        if (idx + i < n) out[idx + i] += add;
    if (blockIdx.x == 0 && threadIdx.x == 0) out[n] = total;
}

// ================= CSR scatter =================
__global__ void csr_scatter(const int* __restrict__ srcE, const int* __restrict__ dstE,
                            const int* __restrict__ rowptr, int* __restrict__ cursor,
                            int* __restrict__ csr_src, int E) {
    int e = blockIdx.x * blockDim.x + threadIdx.x;
    if (e >= E) return;
    int d = dstE[e];
    int pos = rowptr[d] + atomicAdd(&cursor[d], 1);
    csr_src[pos] = srcE[e];
}

// ================= Hs0 = bf16(dis * x)  (64 cols) =================
__global__ void scale_rows64_bf16(const float* __restrict__ x, const float* __restrict__ dis,
                                  u16* __restrict__ out) {
    int t = blockIdx.x * blockDim.x + threadIdx.x;
    if (t >= N_NODES * 64) return;
    out[t] = f2bf(x[t] * dis[t >> 6]);
}

// ===== CSR aggregate (bf16): out[d] = bf16( dis[d]*(Hs[d] + sum Hs[src]) ) ==
// One wave per node. 16B (8 ch) per lane; G = 64/(C/8) edges in flight.
template<int C>
__global__ void csr_agg_bf16(const u16* __restrict__ Hs, const int* __restrict__ rowptr,
                             const int* __restrict__ csr_src, const float* __restrict__ dis,
                             u16* __restrict__ out) {
    constexpr int LPG = C / 8;        // lanes per row
    constexpr int G   = 64 / LPG;     // concurrent edges
    int node = blockIdx.x * 4 + (threadIdx.x >> 6);
    if (node >= N_NODES) return;
    int lane = threadIdx.x & 63;
    int g  = lane / LPG;
    int cl = lane % LPG;              // channels cl*8 .. cl*8+7
    int s0 = rowptr[node], s1 = rowptr[node + 1];
    float a[8] = {};
    if (g == 0) {
        u16x8 v = *(const u16x8*)&Hs[(size_t)node * C + cl * 8];
        #pragma unroll
        for (int j = 0; j < 8; ++j) a[j] = bf2f(v[j]);
    }
    for (int e = s0 + g; e < s1; e += G) {
        int s = csr_src[e];
        u16x8 v = *(const u16x8*)&Hs[(size_t)s * C + cl * 8];
        #pragma unroll
        for (int j = 0; j < 8; ++j) a[j] += bf2f(v[j]);
    }
    #pragma unroll
    for (int m = LPG; m < 64; m <<= 1)
        #pragma unroll
        for (int j = 0; j < 8; ++j) a[j] += __shfl_xor(a[j], m);
    if (g == 0) {
        float dd = dis[node];
        u16x8 o;
        #pragma unroll
        for (int j = 0; j < 8; ++j) o[j] = f2bf(a[j] * dd);
        *(u16x8*)&out[(size_t)node * C + cl * 8] = o;
    }
}

// ================= chunked mean pool (batch_idx is sorted), bf16 in =========
#define POOL_CHUNK 100
__global__ void pool_chunk(const u16* __restrict__ h, const int* __restrict__ batch,
                           float* __restrict__ pooled, float* __restrict__ counts) {
    int c = threadIdx.x;
    int i0 = blockIdx.x * POOL_CHUNK;
    int i1 = min(i0 + POOL_CHUNK, N_NODES);
    float acc = 0.f;
    int cur = batch[i0], cnt = 0;
    for (int i = i0; i < i1; ++i) {
        int b = batch[i];
        if (b != cur) {
            atomicAdd(&pooled[cur * 256 + c], acc);
            if (c == 0) atomicAdd(&counts[cur], (float)cnt);
            acc = 0.f; cnt = 0; cur = b;
        }
        acc += bf2f(h[(size_t)i * 256 + c]);
        cnt++;
    }
    atomicAdd(&pooled[cur * 256 + c], acc);
    if (c == 0) atomicAdd(&counts[cur], (float)cnt);
}

extern "C" void kernel_launch(void* const* d_in, const int* in_sizes, int n_in,
                              void* d_out, int out_size, void* d_ws, size_t ws_size,
                              hipStream_t stream) {
    // ---- inputs (setup_inputs order) ----
    const float* video = (const float*)d_in[1];
    const float* x     = (const float*)d_in[2];
    const int*   eidx  = (const int*)d_in[3];
    const int*   batch = (const int*)d_in[4];
    // text branch + Wq/Wk are dead: seq-len-1 softmax == 1 -> attn = v.
    const float* Wv  = (const float*)d_in[7],  *bv  = (const float*)d_in[8];
    const float* Wva = (const float*)d_in[13], *bva = (const float*)d_in[14];
    const float* Wo  = (const float*)d_in[15], *bo  = (const float*)d_in[16];
    const float* Wf  = (const float*)d_in[17], *bf  = (const float*)d_in[18];
    const float* G1W = (const float*)d_in[19], *G1b = (const float*)d_in[20];
    const float* G2W = (const float*)d_in[21], *G2b = (const float*)d_in[22];
    const float* G3W = (const float*)d_in[23], *G3b = (const float*)d_in[24];
    const float* Wff = (const float*)d_in[25], *bff = (const float*)d_in[26];
    const float* Wb  = (const float*)d_in[27], *bb  = (const float*)d_in[28];
    const float* Wa  = (const float*)d_in[29], *ba  = (const float*)d_in[30];
    const int* srcE = eidx;
    const int* dstE = eidx + N_EDGES;

    // ---- workspace layout ----
    char* wsc = (char*)d_ws;
    size_t off = 0;
    auto alloc = [&](size_t bytes) { char* p = wsc + off; off += (bytes + 255) & ~(size_t)255; return p; };
    u16*   bufA   = (u16*)  alloc((size_t)NPAD * 256 * 2);   // Hs / h3 (bf16)
    u16*   bufB   = (u16*)  alloc((size_t)NPAD * 128 * 2);   // agg outputs (bf16)
    float* dis    = (float*)alloc(NPAD * 4);
    int*   deg    = (int*)  alloc(NPAD * 4);
    int*   rowptr = (int*)  alloc((N_NODES + 1) * 4);
    int*   cursor = (int*)  alloc(N_NODES * 4);
    int*   csrsrc = (int*)  alloc((size_t)N_EDGES * 4);
    int*   bsum   = (int*)  alloc(128 * 4);
    u16*   g1wt   = (u16*)  alloc(128 * 64 * 2);
    u16*   g2wt   = (u16*)  alloc(128 * 128 * 2);
    u16*   g3wt   = (u16*)  alloc(256 * 128 * 2);
    u16*   WvT    = (u16*)  alloc(512 * 512 * 2);
    u16*   WvaT   = (u16*)  alloc(512 * 512 * 2);
    u16*   WoT    = (u16*)  alloc(512 * 512 * 2);
    u16*   WfT    = (u16*)  alloc(512 * 1024 * 2);
    u16*   vidbf  = (u16*)  alloc(BATCH * 512 * 2);
    u16*   catb   = (u16*)  alloc(BATCH * 1024 * 2);         // [ta | venc]
    u16*   vattnb = (u16*)  alloc(BATCH * 512 * 2);
    u16*   fusedb = (u16*)  alloc(BATCH * 512 * 2);
    float* pooled = (float*)alloc(BATCH * 256 * 4);
    float* counts = (float*)alloc(BATCH * 4);

    const int NB = (N_NODES + 1023) / 1024;   // 98
    const int aggGrid = (N_NODES + 3) / 4;

    // ---- degree, dis, CSR ----
    hipMemsetAsync(deg, 0, NPAD * 4, stream);
    hipMemsetAsync(cursor, 0, N_NODES * 4, stream);
    deg_count<<<(N_EDGES + 255) / 256, 256, 0, stream>>>(dstE, deg, N_EDGES);
    make_dis<<<(NPAD + 255) / 256, 256, 0, stream>>>(deg, dis, NPAD);
    scan1<<<NB, 256, 0, stream>>>(deg, rowptr, bsum, N_NODES);
    scan2<<<1, 64, 0, stream>>>(bsum, NB);
    scan3<<<NB, 256, 0, stream>>>(rowptr, bsum, N_NODES, N_EDGES);
    csr_scatter<<<(N_EDGES + 255) / 256, 256, 0, stream>>>(srcE, dstE, rowptr, cursor, csrsrc, N_EDGES);

    // ---- weight prep (bf16 transposes) ----
    transpose_w<<<(64 * 128 + 255) / 256, 256, 0, stream>>>(G1W, g1wt, 64, 128);
    transpose_w<<<(128 * 128 + 255) / 256, 256, 0, stream>>>(G2W, g2wt, 128, 128);
    transpose_w<<<(128 * 256 + 255) / 256, 256, 0, stream>>>(G3W, g3wt, 128, 256);
    transpose_w<<<(512 * 512 + 255) / 256, 256, 0, stream>>>(Wv, WvT, 512, 512);
    transpose_w<<<(512 * 512 + 255) / 256, 256, 0, stream>>>(Wva, WvaT, 512, 512);
    transpose_w<<<(512 * 512 + 255) / 256, 256, 0, stream>>>(Wo, WoT, 512, 512);
    transpose_w<<<(1024 * 512 + 255) / 256, 256, 0, stream>>>(Wf, WfT, 1024, 512);
    f32_to_bf16<<<(BATCH * 512 + 255) / 256, 256, 0, stream>>>(video, vidbf, BATCH * 512);

    // ---- front-end on MFMA (attn collapses: attn = v) ----
    // venc -> cat[:,512:1024]; ta -> cat[:,0:512]; fused = relu(cat@Wf+bf)
    dim3 feGrid(4, 2);
    gemm_loop<1><<<feGrid, 256, 0, stream>>>(vidbf, WvT, bv, catb + 512, 512, 512, 512, 1024);
    gemm_loop<0><<<feGrid, 256, 0, stream>>>(catb + 512, WvaT, bva, vattnb, 512, 512, 1024, 512);
    gemm_loop<0><<<feGrid, 256, 0, stream>>>(vattnb, WoT, bo, catb, 512, 512, 512, 1024);
    gemm_loop<1><<<feGrid, 256, 0, stream>>>(catb, WfT, bf, fusedb, 512, 1024, 1024, 512);

    // ---- GCN stack: aggregate-first, bf16 features, MFMA GEMMs ----
    scale_rows64_bf16<<<(N_NODES * 64 + 255) / 256, 256, 0, stream>>>(x, dis, bufA);
    csr_agg_bf16<64><<<aggGrid, 256, 0, stream>>>(bufA, rowptr, csrsrc, dis, bufB);
    gemm_mfma<64, 2, 1><<<dim3(1, NPAD / 128), 256, 0, stream>>>(bufB, g1wt, G1b, dis, bufA, 128);
    csr_agg_bf16<128><<<aggGrid, 256, 0, stream>>>(bufA, rowptr, csrsrc, dis, bufB);
    gemm_mfma<128, 2, 1><<<dim3(1, NPAD / 128), 256, 0, stream>>>(bufB, g2wt, G2b, dis, bufA, 128);
    csr_agg_bf16<128><<<aggGrid, 256, 0, stream>>>(bufA, rowptr, csrsrc, dis, bufB);
    gemm_mfma<128, 0, 0><<<dim3(2, NPAD / 128), 256, 0, stream>>>(bufB, g3wt, G3b, nullptr, bufA, 256);

    // ---- per-graph mean pool ----
    hipMemsetAsync(pooled, 0, (BATCH * 256 + BATCH) * 4, stream);
    pool_chunk<<<(N_NODES + POOL_CHUNK - 1) / POOL_CHUNK, 256, 0, stream>>>(bufA, batch, pooled, counts);

    // ---- fused tail ----
    final_fused<<<BATCH, 256, 0, stream>>>(fusedb, pooled, counts, Wff, bff, Wb, bb, Wa, ba, (float*)d_out);
}

// Round 6
// 478.154 us; speedup vs baseline: 25.9531x; 1.2468x over previous
//
#include <hip/hip_runtime.h>
#include <hip/hip_bf16.h>

#define N_NODES 100000
#define NPAD    100096          // 782 * 128
#define N_EDGES 1600000
#define BATCH   256
#define HDIM    512

typedef unsigned short u16;
typedef __attribute__((ext_vector_type(8))) short bf16x8;
typedef __attribute__((ext_vector_type(8))) unsigned short u16x8;
typedef __attribute__((ext_vector_type(4))) float f32x4;

__device__ __forceinline__ float bf2f(u16 u) {
    union { unsigned i; float f; } v; v.i = ((unsigned)u) << 16; return v.f;
}
__device__ __forceinline__ u16 f2bf(float f) {
    __hip_bfloat16 h = __float2bfloat16(f);
    return *reinterpret_cast<u16*>(&h);
}

// ============ MFMA GEMM (node path): C = act(A[M,K]@W) , K<=128, 1 stage =====
// A: [M][K] bf16. Wt: [N][K] bf16. 128x128 tile, 4 waves 2x2, 4x4 frags of
// 16x16x32. LDS via global_load_lds w=16, pre-swizzled source (rule 21).
// ACT: 0 none, 2 elu. SCALE: multiply by dis[row] after act.
template<int K, int ACT, int SCALE>
__global__ __launch_bounds__(256) void gemm_mfma(
        const u16* __restrict__ A, const u16* __restrict__ Wt,
        const float* __restrict__ bias, const float* __restrict__ dis,
        u16* __restrict__ C, int N) {
    constexpr int RB = K * 2;                 // row bytes
    __shared__ u16 As[128 * K];
    __shared__ u16 Bs[128 * K];
    const int tid  = threadIdx.x;
    const int lane = tid & 63;
    const int w    = tid >> 6;
    const int wr   = w >> 1, wc = w & 1;
    const int row0 = blockIdx.y * 128;
    const int col0 = blockIdx.x * 128;

    constexpr int WB     = 128 * RB / 4;
    constexpr int PASSES = WB / 1024;
    const size_t Abase = (size_t)row0 * K;
    const size_t Bbase = (size_t)col0 * K;
    #pragma unroll
    for (int p = 0; p < PASSES; ++p) {
        int Lb  = w * WB + p * 1024;
        int L   = Lb + lane * 16;
        int row = L / RB;
        int cb  = L % RB;
        int scb = cb ^ ((row & 7) << 4);
        const u16* ga = A  + Abase + (size_t)row * K + (scb >> 1);
        const u16* gb = Wt + Bbase + (size_t)row * K + (scb >> 1);
        __builtin_amdgcn_global_load_lds((const __attribute__((address_space(1))) void*)ga,
            (__attribute__((address_space(3))) void*)&As[Lb >> 1], 16, 0, 0);
        __builtin_amdgcn_global_load_lds((const __attribute__((address_space(1))) void*)gb,
            (__attribute__((address_space(3))) void*)&Bs[Lb >> 1], 16, 0, 0);
    }
    asm volatile("s_waitcnt vmcnt(0)" ::: "memory");
    __syncthreads();

    const int rl = lane & 15;
    const int kg = lane >> 4;
    f32x4 acc[4][4] = {};
    #pragma unroll
    for (int s = 0; s < K / 32; ++s) {
        bf16x8 af[4], bg[4];
        #pragma unroll
        for (int m = 0; m < 4; ++m) {
            int row = wr * 64 + m * 16 + rl;
            int cb  = s * 64 + kg * 16;
            int scb = cb ^ ((row & 7) << 4);
            af[m] = *(const bf16x8*)&As[(row * RB + scb) >> 1];
        }
        #pragma unroll
        for (int n = 0; n < 4; ++n) {
            int row = wc * 64 + n * 16 + rl;
            int cb  = s * 64 + kg * 16;
            int scb = cb ^ ((row & 7) << 4);
            bg[n] = *(const bf16x8*)&Bs[(row * RB + scb) >> 1];
        }
        #pragma unroll
        for (int m = 0; m < 4; ++m)
            #pragma unroll
            for (int n = 0; n < 4; ++n)
                acc[m][n] = __builtin_amdgcn_mfma_f32_16x16x32_bf16(af[m], bg[n], acc[m][n], 0, 0, 0);
    }

    #pragma unroll
    for (int m = 0; m < 4; ++m) {
        #pragma unroll
        for (int r = 0; r < 4; ++r) {
            int grow = row0 + wr * 64 + m * 16 + kg * 4 + r;
            float ds = SCALE ? dis[grow] : 1.f;
            #pragma unroll
            for (int n = 0; n < 4; ++n) {
                int gcol = col0 + wc * 64 + n * 16 + rl;
                float v = acc[m][n][r] + bias[gcol];
                if (ACT == 2) v = v > 0.f ? v : expm1f(v);
                C[(size_t)grow * N + gcol] = f2bf(v * ds);
            }
        }
    }
}

// ======== MFMA GEMM (front-end): K-loop (BK=64), runtime lda/ldc =============
// ACT: 0 none, 1 relu.
template<int ACT>
__global__ __launch_bounds__(256) void gemm_loop(
        const u16* __restrict__ A, const u16* __restrict__ Wt,
        const float* __restrict__ bias, u16* __restrict__ C,
        int N, int K, int lda, int ldc) {
    __shared__ u16 As[128 * 64];
    __shared__ u16 Bs[128 * 64];
    const int tid  = threadIdx.x;
    const int lane = tid & 63;
    const int w    = tid >> 6;
    const int wr   = w >> 1, wc = w & 1;
    const int row0 = blockIdx.y * 128;
    const int col0 = blockIdx.x * 128;
    const int rl = lane & 15;
    const int kg = lane >> 4;
    f32x4 acc[4][4] = {};

    for (int k0 = 0; k0 < K; k0 += 64) {
        #pragma unroll
        for (int p = 0; p < 4; ++p) {
            int Lb  = w * 4096 + p * 1024;
            int L   = Lb + lane * 16;
            int row = L >> 7;
            int cb  = L & 127;
            int scb = cb ^ ((row & 7) << 4);
            const u16* ga = A  + (size_t)(row0 + row) * lda + k0 + (scb >> 1);
            const u16* gb = Wt + (size_t)(col0 + row) * K   + k0 + (scb >> 1);
            __builtin_amdgcn_global_load_lds((const __attribute__((address_space(1))) void*)ga,
                (__attribute__((address_space(3))) void*)&As[Lb >> 1], 16, 0, 0);
            __builtin_amdgcn_global_load_lds((const __attribute__((address_space(1))) void*)gb,
                (__attribute__((address_space(3))) void*)&Bs[Lb >> 1], 16, 0, 0);
        }
        asm volatile("s_waitcnt vmcnt(0)" ::: "memory");
        __syncthreads();
        #pragma unroll
        for (int s = 0; s < 2; ++s) {
            bf16x8 af[4], bg[4];
            #pragma unroll
            for (int m = 0; m < 4; ++m) {
                int row = wr * 64 + m * 16 + rl;
                int cb  = s * 64 + kg * 16;
                int scb = cb ^ ((row & 7) << 4);
                af[m] = *(const bf16x8*)&As[(row * 128 + scb) >> 1];
            }
            #pragma unroll
            for (int n = 0; n < 4; ++n) {
                int row = wc * 64 + n * 16 + rl;
                int cb  = s * 64 + kg * 16;
                int scb = cb ^ ((row & 7) << 4);
                bg[n] = *(const bf16x8*)&Bs[(row * 128 + scb) >> 1];
            }
            #pragma unroll
            for (int m = 0; m < 4; ++m)
                #pragma unroll
                for (int n = 0; n < 4; ++n)
                    acc[m][n] = __builtin_amdgcn_mfma_f32_16x16x32_bf16(af[m], bg[n], acc[m][n], 0, 0, 0);
        }
        __syncthreads();
    }

    #pragma unroll
    for (int m = 0; m < 4; ++m) {
        #pragma unroll
        for (int r = 0; r < 4; ++r) {
            int grow = row0 + wr * 64 + m * 16 + kg * 4 + r;
            #pragma unroll
            for (int n = 0; n < 4; ++n) {
                int gcol = col0 + wc * 64 + n * 16 + rl;
                float v = acc[m][n][r] + bias[gcol];
                if (ACT == 1) v = fmaxf(v, 0.f);
                C[(size_t)grow * ldc + gcol] = f2bf(v);
            }
        }
    }
}

// ===== fused prep: all weight transposes (f32 [K,N] -> bf16 [N,K]) + video ==
template<int K, int N>
__device__ __forceinline__ void tw(const float* __restrict__ W, u16* __restrict__ Wt, int t) {
    int n = t / K, k = t - n * K;
    Wt[t] = f2bf(W[(size_t)k * N + n]);
}

__global__ void prep(const float* __restrict__ G1W, u16* __restrict__ g1wt,
                     const float* __restrict__ G2W, u16* __restrict__ g2wt,
                     const float* __restrict__ Wv,  u16* __restrict__ WvT,
                     const float* __restrict__ Wva, u16* __restrict__ WvaT,
                     const float* __restrict__ Wo,  u16* __restrict__ WoT,
                     const float* __restrict__ Wf,  u16* __restrict__ WfT,
                     const float* __restrict__ video, u16* __restrict__ vidbf) {
    const int bid = blockIdx.x, tid = threadIdx.x;
    if (bid < 32)        { tw<64, 128>  (G1W, g1wt, bid * 256 + tid); }
    else if (bid < 96)   { tw<128, 128> (G2W, g2wt, (bid - 32) * 256 + tid); }
    else if (bid < 1120) { tw<512, 512> (Wv,  WvT,  (bid - 96) * 256 + tid); }
    else if (bid < 2144) { tw<512, 512> (Wva, WvaT, (bid - 1120) * 256 + tid); }
    else if (bid < 3168) { tw<512, 512> (Wo,  WoT,  (bid - 2144) * 256 + tid); }
    else if (bid < 5216) { tw<1024, 512>(Wf,  WfT,  (bid - 3168) * 256 + tid); }
    else { int t = (bid - 5216) * 256 + tid; vidbf[t] = f2bf(video[t]); }
}

// == fused tail: pooled256 = (pool/cnt)@G3W+b3; final = relu([f|p]@Wff); heads
__global__ void final_fused(const u16* __restrict__ fusedb,
                            const float* __restrict__ pooled, const float* __restrict__ counts,
                            const float* __restrict__ G3W, const float* __restrict__ G3b,
                            const float* __restrict__ Wff, const float* __restrict__ bff,
                            const float* __restrict__ Wb,  const float* __restrict__ bb,
                            const float* __restrict__ Wa,  const float* __restrict__ ba,
                            float* __restrict__ out) {
    __shared__ float cat[768], fin[512], pp[128];
    __shared__ float rd[4][4];
    const int b = blockIdx.x, tid = threadIdx.x;
    cat[tid] = bf2f(fusedb[b * 512 + tid]);
    cat[tid + 256] = bf2f(fusedb[b * 512 + 256 + tid]);
    float inv = 1.f / counts[b];
    if (tid < 128) pp[tid] = pooled[b * 128 + tid] * inv;
    __syncthreads();
    {   // pooled256 = pp @ G3W + G3b  (SegMean commutes with the affine GCN3)
        float s = G3b[tid];
        #pragma unroll 8
        for (int k = 0; k < 128; ++k) s += pp[k] * G3W[k * 256 + tid];
        cat[512 + tid] = s;
    }
    __syncthreads();
    {
        float a0 = bff[tid], a1 = bff[tid + 256];
        #pragma unroll 8
        for (int k = 0; k < 768; ++k) {
            float xv = cat[k];
            a0 += xv * Wff[k * 512 + tid];
            a1 += xv * Wff[k * 512 + tid + 256];
        }
        fin[tid] = fmaxf(a0, 0.f);
        fin[tid + 256] = fmaxf(a1, 0.f);
    }
    __syncthreads();
    float z0 = 0.f, z1 = 0.f, y0 = 0.f, y1 = 0.f;
    for (int k = tid; k < 512; k += 256) {
        float f = fin[k];
        z0 += f * Wb[2 * k];
        z1 += f * Wb[2 * k + 1];
        y0 += f * Wa[2 * k];
        y1 += f * Wa[2 * k + 1];
    }
    #pragma unroll
    for (int off = 32; off > 0; off >>= 1) {
        z0 += __shfl_down(z0, off);
        z1 += __shfl_down(z1, off);
        y0 += __shfl_down(y0, off);
        y1 += __shfl_down(y1, off);
    }
    int ww = tid >> 6;
    if ((tid & 63) == 0) { rd[ww][0] = z0; rd[ww][1] = z1; rd[ww][2] = y0; rd[ww][3] = y1; }
    __syncthreads();
    if (tid == 0) {
        float Z0 = rd[0][0] + rd[1][0] + rd[2][0] + rd[3][0] + bb[0];
        float Z1 = rd[0][1] + rd[1][1] + rd[2][1] + rd[3][1] + bb[1];
        float Y0 = rd[0][2] + rd[1][2] + rd[2][2] + rd[3][2] + ba[0];
        float Y1 = rd[0][3] + rd[1][3] + rd[2][3] + rd[3][3] + ba[1];
        float m = fmaxf(Z0, Z1);
        float l = m + logf(expf(Z0 - m) + expf(Z1 - m));
        out[b * 2 + 0] = Z0 - l;
        out[b * 2 + 1] = Z1 - l;
        float m2 = fmaxf(Y0, Y1);
        float l2 = m2 + logf(expf(Y0 - m2) + expf(Y1 - m2));
        out[512 + b * 2 + 0] = Y0 - l2;
        out[512 + b * 2 + 1] = Y1 - l2;
    }
}

// ============ CSR build: histogram + slot in ONE atomic pass =================
__global__ void deg_slot(const int* __restrict__ dstE, int* __restrict__ deg,
                         int* __restrict__ slot, int E) {
    int e = blockIdx.x * blockDim.x + threadIdx.x;
    if (e < E) slot[e] = atomicAdd(&deg[dstE[e]], 1);
}

// scan1: block-local exclusive scan of deg (1024/block) + fused dis = rsqrt
__global__ void scan1(const int* __restrict__ in, int* __restrict__ out,
                      int* __restrict__ bsum, float* __restrict__ dis, int n) {
    __shared__ int ts[256];
    const int tid = threadIdx.x;
    const int base = blockIdx.x * 1024;
    int v[4];
    #pragma unroll
    for (int i = 0; i < 4; ++i) {
        int idx = base + tid * 4 + i;
        v[i] = (idx < n) ? in[idx] : 0;
        if (idx < NPAD) dis[idx] = rsqrtf((float)v[i] + 1.f);
    }
    ts[tid] = v[0] + v[1] + v[2] + v[3];
    __syncthreads();
    for (int off = 1; off < 256; off <<= 1) {
        int val = (tid >= off) ? ts[tid - off] : 0;
        __syncthreads();
        ts[tid] += val;
        __syncthreads();
    }
    int run = (tid == 0) ? 0 : ts[tid - 1];
    if (tid == 255) bsum[blockIdx.x] = ts[255];
    #pragma unroll
    for (int i = 0; i < 4; ++i) {
        int idx = base + tid * 4 + i;
        if (idx < n) out[idx] = run;
        run += v[i];
    }
}

// scan2: one-wave shfl scan over <=128 block sums
__global__ void scan2(int* __restrict__ bsum, int nb) {
    int l = threadIdx.x;                       // 64 threads
    int a = (l < nb) ? bsum[l] : 0;
    int b = (l + 64 < nb) ? bsum[l + 64] : 0;
    int oa = a, ob = b;
    #pragma unroll
    for (int off = 1; off < 64; off <<= 1) {
        int t = __shfl_up(a, off);
        if (l >= off) a += t;
    }
    int totA = __shfl(a, 63);
    #pragma unroll
    for (int off = 1; off < 64; off <<= 1) {
        int t = __shfl_up(b, off);
        if (l >= off) b += t;
    }
    if (l < nb) bsum[l] = a - oa;
    if (l + 64 < nb) bsum[l + 64] = totA + b - ob;
}

__global__ void scan3(int* __restrict__ out, const int* __restrict__ bsum, int n, int total) {
    int idx = blockIdx.x * 1024 + threadIdx.x * 4;
    int add = bsum[blockIdx.x];
    #pragma unroll
    for (int i = 0; i < 4; ++i)
        if (idx + i < n) out[idx + i] += add;
    if (blockIdx.x == 0 && threadIdx.x == 0) out[n] = total;
}

// atomic-free scatter: pos = rowptr[dst] + slot
__global__ void csr_scatter2(const int* __restrict__ srcE, const int* __restrict__ dstE,
                             const int* __restrict__ rowptr, const int* __restrict__ slot,
                             int* __restrict__ csr_src, int E) {
    int e = blockIdx.x * blockDim.x + threadIdx.x;
    if (e >= E) return;
    csr_src[rowptr[dstE[e]] + slot[e]] = srcE[e];
}

// ================= Hs0 = bf16(dis * x)  (64 cols) =================
__global__ void scale_rows64_bf16(const float* __restrict__ x, const float* __restrict__ dis,
                                  u16* __restrict__ out) {
    int t = blockIdx.x * blockDim.x + threadIdx.x;
    if (t >= N_NODES * 64) return;
    out[t] = f2bf(x[t] * dis[t >> 6]);
}

// ===== CSR aggregate (bf16): out[d] = bf16( dis[d]*(Hs[d] + sum Hs[src]) ) ==
// One wave per node; 16B (8ch)/lane; G concurrent edge slots; 2x unrolled.
template<int C>
__global__ void csr_agg_bf16(const u16* __restrict__ Hs, const int* __restrict__ rowptr,
                             const int* __restrict__ csr_src, const float* __restrict__ dis,
                             u16* __restrict__ out) {
    constexpr int LPG = C / 8;        // lanes per row
    constexpr int G   = 64 / LPG;     // concurrent edges
    int node = blockIdx.x * 4 + (threadIdx.x >> 6);
    if (node >= N_NODES) return;
    int lane = threadIdx.x & 63;
    int g  = lane / LPG;
    int cl = lane % LPG;
    int s0 = rowptr[node], s1 = rowptr[node + 1];
    float a[8] = {};
    if (g == 0) {
        u16x8 v = *(const u16x8*)&Hs[(size_t)node * C + cl * 8];
        #pragma unroll
        for (int j = 0; j < 8; ++j) a[j] = bf2f(v[j]);
    }
    int e = s0 + g;
    while (e + G < s1) {
        int sA = csr_src[e], sB = csr_src[e + G];
        u16x8 vA = *(const u16x8*)&Hs[(size_t)sA * C + cl * 8];
        u16x8 vB = *(const u16x8*)&Hs[(size_t)sB * C + cl * 8];
        #pragma unroll
        for (int j = 0; j < 8; ++j) a[j] += bf2f(vA[j]) + bf2f(vB[j]);
        e += 2 * G;
    }
    while (e < s1) {
        int s = csr_src[e];
        u16x8 v = *(const u16x8*)&Hs[(size_t)s * C + cl * 8];
        #pragma unroll
        for (int j = 0; j < 8; ++j) a[j] += bf2f(v[j]);
        e += G;
    }
    #pragma unroll
    for (int m = LPG; m < 64; m <<= 1)
        #pragma unroll
        for (int j = 0; j < 8; ++j) a[j] += __shfl_xor(a[j], m);
    if (g == 0) {
        float dd = dis[node];
        u16x8 o;
        #pragma unroll
        for (int j = 0; j < 8; ++j) o[j] = f2bf(a[j] * dd);
        *(u16x8*)&out[(size_t)node * C + cl * 8] = o;
    }
}

// ===== fused layer-3 agg + segment-sum pool: pooled[b] += dis[d]*(...) ======
// 16 consecutive nodes/block (sorted batch => <=2 graph bins), LDS staging.
__global__ __launch_bounds__(256) void csr_agg_pool(
        const u16* __restrict__ Hs, const int* __restrict__ rowptr,
        const int* __restrict__ csr_src, const float* __restrict__ dis,
        const int* __restrict__ batch,
        float* __restrict__ pooled, float* __restrict__ counts) {
    __shared__ float bins[2][128];
    __shared__ int cnt[2];
    const int tid = threadIdx.x;
    const int base = blockIdx.x * 16;
    if (tid < 128) { bins[0][tid] = 0.f; bins[1][tid] = 0.f; }
    if (tid < 2) cnt[tid] = 0;
    __syncthreads();
    const int lane = tid & 63;
    const int w = tid >> 6;
    const int g = lane >> 4;          // LPG=16, G=4
    const int cl = lane & 15;
    const int b0 = batch[base];
    #pragma unroll
    for (int i = 0; i < 4; ++i) {
        const int node = base + w * 4 + i;
        const int s0 = rowptr[node], s1 = rowptr[node + 1];
        float a[8] = {};
        if (g == 0) {
            u16x8 v = *(const u16x8*)&Hs[(size_t)node * 128 + cl * 8];
            #pragma unroll
            for (int j = 0; j < 8; ++j) a[j] = bf2f(v[j]);
        }
        int e = s0 + g;
        while (e + 4 < s1) {
            int sA = csr_src[e], sB = csr_src[e + 4];
            u16x8 vA = *(const u16x8*)&Hs[(size_t)sA * 128 + cl * 8];
            u16x8 vB = *(const u16x8*)&Hs[(size_t)sB * 128 + cl * 8];
            #pragma unroll
            for (int j = 0; j < 8; ++j) a[j] += bf2f(vA[j]) + bf2f(vB[j]);
            e += 8;
        }
        while (e < s1) {
            int s = csr_src[e];
            u16x8 v = *(const u16x8*)&Hs[(size_t)s * 128 + cl * 8];
            #pragma unroll
            for (int j = 0; j < 8; ++j) a[j] += bf2f(v[j]);
            e += 4;
        }
        #pragma unroll
        for (int m = 16; m < 64; m <<= 1)
            #pragma unroll
            for (int j = 0; j < 8; ++j) a[j] += __shfl_xor(a[j], m);
        if (g == 0) {
            int bin = (batch[node] != b0) ? 1 : 0;
            float dd = dis[node];
            #pragma unroll
            for (int j = 0; j < 8; ++j) atomicAdd(&bins[bin][cl * 8 + j], a[j] * dd);
            if (cl == 0) atomicAdd(&cnt[bin], 1);
        }
    }
    __syncthreads();
    int bin = tid >> 7, c = tid & 127;
    if (cnt[bin] > 0) atomicAdd(&pooled[(b0 + bin) * 128 + c], bins[bin][c]);
    if (tid < 2 && cnt[tid] > 0) atomicAdd(&counts[b0 + tid], (float)cnt[tid]);
}

extern "C" void kernel_launch(void* const* d_in, const int* in_sizes, int n_in,
                              void* d_out, int out_size, void* d_ws, size_t ws_size,
                              hipStream_t stream) {
    // ---- inputs (setup_inputs order) ----
    const float* video = (const float*)d_in[1];
    const float* x     = (const float*)d_in[2];
    const int*   eidx  = (const int*)d_in[3];
    const int*   batch = (const int*)d_in[4];
    // text branch + Wq/Wk are dead: seq-len-1 softmax == 1 -> attn = v.
    const float* Wv  = (const float*)d_in[7],  *bv  = (const float*)d_in[8];
    const float* Wva = (const float*)d_in[13], *bva = (const float*)d_in[14];
    const float* Wo  = (const float*)d_in[15], *bo  = (const float*)d_in[16];
    const float* Wf  = (const float*)d_in[17], *bf  = (const float*)d_in[18];
    const float* G1W = (const float*)d_in[19], *G1b = (const float*)d_in[20];
    const float* G2W = (const float*)d_in[21], *G2b = (const float*)d_in[22];
    const float* G3W = (const float*)d_in[23], *G3b = (const float*)d_in[24];
    const float* Wff = (const float*)d_in[25], *bff = (const float*)d_in[26];
    const float* Wb  = (const float*)d_in[27], *bb  = (const float*)d_in[28];
    const float* Wa  = (const float*)d_in[29], *ba  = (const float*)d_in[30];
    const int* srcE = eidx;
    const int* dstE = eidx + N_EDGES;

    // ---- workspace layout ----
    char* wsc = (char*)d_ws;
    size_t off = 0;
    auto alloc = [&](size_t bytes) { char* p = wsc + off; off += (bytes + 255) & ~(size_t)255; return p; };
    u16*   bufA   = (u16*)  alloc((size_t)NPAD * 128 * 2);   // Hs (bf16)
    u16*   bufB   = (u16*)  alloc((size_t)NPAD * 128 * 2);   // agg outputs (bf16)
    float* dis    = (float*)alloc(NPAD * 4);
    int*   deg    = (int*)  alloc(NPAD * 4);
    int*   rowptr = (int*)  alloc((N_NODES + 1) * 4);
    int*   slot   = (int*)  alloc((size_t)N_EDGES * 4);
    int*   csrsrc = (int*)  alloc((size_t)N_EDGES * 4);
    int*   bsum   = (int*)  alloc(128 * 4);
    u16*   g1wt   = (u16*)  alloc(128 * 64 * 2);
    u16*   g2wt   = (u16*)  alloc(128 * 128 * 2);
    u16*   WvT    = (u16*)  alloc(512 * 512 * 2);
    u16*   WvaT   = (u16*)  alloc(512 * 512 * 2);
    u16*   WoT    = (u16*)  alloc(512 * 512 * 2);
    u16*   WfT    = (u16*)  alloc(512 * 1024 * 2);
    u16*   vidbf  = (u16*)  alloc(BATCH * 512 * 2);
    u16*   catb   = (u16*)  alloc(BATCH * 1024 * 2);         // [ta | venc]
    u16*   vattnb = (u16*)  alloc(BATCH * 512 * 2);
    u16*   fusedb = (u16*)  alloc(BATCH * 512 * 2);
    float* pooled = (float*)alloc((BATCH * 128 + BATCH) * 4);
    float* counts = pooled + BATCH * 128;

    const int NB = (N_NODES + 1023) / 1024;   // 98
    const int aggGrid = (N_NODES + 3) / 4;

    // ---- CSR build: one atomic pass + scan + atomic-free scatter ----
    hipMemsetAsync(deg, 0, NPAD * 4, stream);
    hipMemsetAsync(pooled, 0, (BATCH * 128 + BATCH) * 4, stream);
    deg_slot<<<(N_EDGES + 255) / 256, 256, 0, stream>>>(dstE, deg, slot, N_EDGES);
    scan1<<<NB, 256, 0, stream>>>(deg, rowptr, bsum, dis, N_NODES);
    scan2<<<1, 64, 0, stream>>>(bsum, NB);
    scan3<<<NB, 256, 0, stream>>>(rowptr, bsum, N_NODES, N_EDGES);
    csr_scatter2<<<(N_EDGES + 255) / 256, 256, 0, stream>>>(srcE, dstE, rowptr, slot, csrsrc, N_EDGES);

    // ---- fused prep (weight transposes + video cast) ----
    prep<<<5728, 256, 0, stream>>>(G1W, g1wt, G2W, g2wt, Wv, WvT, Wva, WvaT,
                                   Wo, WoT, Wf, WfT, video, vidbf);

    // ---- front-end on MFMA (attn collapses: attn = v) ----
    dim3 feGrid(4, 2);
    gemm_loop<1><<<feGrid, 256, 0, stream>>>(vidbf, WvT, bv, catb + 512, 512, 512, 512, 1024);
    gemm_loop<0><<<feGrid, 256, 0, stream>>>(catb + 512, WvaT, bva, vattnb, 512, 512, 1024, 512);
    gemm_loop<0><<<feGrid, 256, 0, stream>>>(vattnb, WoT, bo, catb, 512, 512, 512, 1024);
    gemm_loop<1><<<feGrid, 256, 0, stream>>>(catb, WfT, bf, fusedb, 512, 1024, 1024, 512);

    // ---- GCN stack: aggregate-first, bf16 features, MFMA GEMMs ----
    scale_rows64_bf16<<<(N_NODES * 64 + 255) / 256, 256, 0, stream>>>(x, dis, bufA);
    csr_agg_bf16<64><<<aggGrid, 256, 0, stream>>>(bufA, rowptr, csrsrc, dis, bufB);
    gemm_mfma<64, 2, 1><<<dim3(1, NPAD / 128), 256, 0, stream>>>(bufB, g1wt, G1b, dis, bufA, 128);
    csr_agg_bf16<128><<<aggGrid, 256, 0, stream>>>(bufA, rowptr, csrsrc, dis, bufB);
    gemm_mfma<128, 2, 1><<<dim3(1, NPAD / 128), 256, 0, stream>>>(bufB, g2wt, G2b, dis, bufA, 128);
    // layer-3 agg fused with segment pooling (GEMM3 deferred to final_fused)
    csr_agg_pool<<<N_NODES / 16, 256, 0, stream>>>(bufA, rowptr, csrsrc, dis, batch, pooled, counts);

    // ---- fused tail: mean + G3W matvec + concat + Wff + heads ----
    final_fused<<<BATCH, 256, 0, stream>>>(fusedb, pooled, counts, G3W, G3b,
                                           Wff, bff, Wb, bb, Wa, ba, (float*)d_out);
}